// Round 7
// baseline (130.581 us; speedup 1.0000x reference)
//
#include <hip/hip_runtime.h>
#include <stdint.h>

#define B 64
#define G 32
#define A 25600
#define NC 2
#define NL 5
#define IOU_T 0.5f
#define VAR_C 0.1f
#define VAR_S 0.2f

#define MSPLIT 100
#define MCH (A / MSPLIT)    // 256 anchors per match block, 1 iter
#define LSPLIT 16
#define LCH (A / LSPLIT)    // 1600 anchors per loss block
#define PF 8                // fields per psplit record

#define NB 2048             // value-histogram bins
#define BSCALE 100.0f       // bin = int(closs * 100), clamped
#define CANDCAP 8192        // per-batch candidate buffer capacity

__device__ __forceinline__ float sl1(float x) {
    float ax = fabsf(x);
    return ax < 1.0f ? 0.5f * ax * ax : ax - 0.5f;
}

// ---------------------------------------------------------------------------
// K0: zero gbest + ghist + bcnt + gdone (contiguous u32 region).
// ---------------------------------------------------------------------------
__global__ void init_kernel(unsigned* __restrict__ zr, int n) {
    int i = blockIdx.x * blockDim.x + threadIdx.x;
    if (i < n) zr[i] = 0u;
}

// ---------------------------------------------------------------------------
// K1: grid (B, MSPLIT) x 256.  (unchanged from r6)
// ---------------------------------------------------------------------------
__global__ __launch_bounds__(256) void match_kernel(
    const float* __restrict__ anchors, const float* __restrict__ gt_boxes,
    const int* __restrict__ gt_labels, signed char* __restrict__ matches,
    unsigned long long* __restrict__ gbest)
{
    const int b = blockIdx.x, s = blockIdx.y, tid = threadIdx.x;
    const int lane = tid & 63;
    __shared__ float4 sbox[G];
    __shared__ int sgorig[G];
    __shared__ unsigned long long sbest[G];
    __shared__ int s_nv;

    if (tid < G) {
        sbest[tid] = 0ULL;
        int valid = gt_labels[b * G + tid] > 0;
        unsigned long long mask = __ballot(valid);
        int pfx = __popcll(mask & ((1ULL << tid) - 1ULL));
        if (valid) {
            sbox[pfx] = *(const float4*)(gt_boxes + (b * G + tid) * 4);
            sgorig[pfx] = tid;
        }
        if (tid == 0) s_nv = (int)__popcll(mask);
    }
    __syncthreads();
    const int nv = s_nv;

    signed char* mrow = matches + (size_t)b * A;
    const int a = s * MCH + tid;

    float4 an = *(const float4*)(anchors + a * 4);
    float ax0 = an.x - an.z * 0.5f, ay0 = an.y - an.w * 0.5f;
    float ax1 = an.x + an.z * 0.5f, ay1 = an.y + an.w * 0.5f;
    float aa = (ax1 - ax0) * (ay1 - ay0);   // mirror reference float path

    float best_iou = -2.0f; int best_ci = 0;
    for (int ci = 0; ci < nv; ++ci) {
        float4 bb = sbox[ci];
        float area = (bb.z - bb.x) * (bb.w - bb.y);
        float tlx = fmaxf(bb.x, ax0), tly = fmaxf(bb.y, ay0);
        float brx = fminf(bb.z, ax1), bry = fminf(bb.w, ay1);
        float iw = fmaxf(brx - tlx, 0.0f), ih = fmaxf(bry - tly, 0.0f);
        float inter = iw * ih;
        float iou = 0.0f;                           // exact: 0/den == +0.0
        if (__any(inter > 0.0f)) {                  // wave-uniform skip
            iou = inter / (area + aa - inter + 1e-9f);
            unsigned long long key =
                ((unsigned long long)__float_as_uint(iou) << 32) |
                (unsigned)(0xFFFFFFFFu - (unsigned)a);
            #pragma unroll
            for (int off = 32; off > 0; off >>= 1) {
                unsigned long long o = __shfl_down(key, off);
                if (o > key) key = o;
            }
            if (lane == 0 && key > sbest[ci]) atomicMax(&sbest[ci], key);
        }
        if (iou > best_iou) { best_iou = iou; best_ci = ci; }  // first-max wins
    }
    mrow[a] = (best_iou >= IOU_T) ? (signed char)sgorig[best_ci]
                                  : (signed char)(-1);
    __syncthreads();
    if (tid < nv && sbest[tid] != 0ULL)
        atomicMax(&gbest[b * G + sgorig[tid]], sbest[tid]);
}

// ---------------------------------------------------------------------------
// K2 MEGA: grid (B, LSPLIT) x 256.
// Phase A (all blocks): loss partial sums + negkey + LDS 2048-bin neg hist
//   merged to ghist[b].  Forced matches via gbest overlay.
// Phase B (last block per batch, via threadfence+counter): top-k select for
//   the batch: threshold bin from ghist, one fused sum+compact scan, exact
//   radix over in-bin candidates, deterministic sum -> partials[b].
// Phase C (last batch's selector): finalize 5 scalar outputs.
// ---------------------------------------------------------------------------
__global__ __launch_bounds__(256) void loss_select_kernel(
    const float* __restrict__ cls_logits, const float* __restrict__ box_preds,
    const float* __restrict__ lmk_preds, const float* __restrict__ gaze_preds,
    const float* __restrict__ anchors, const float* __restrict__ gt_boxes,
    const int* __restrict__ gt_labels, const float* __restrict__ gt_lmk,
    const float* __restrict__ gt_gaze, const signed char* __restrict__ matches,
    const unsigned long long* __restrict__ gbest,
    unsigned* __restrict__ negkey, unsigned* __restrict__ ghist,
    float* __restrict__ psplit, unsigned* __restrict__ candbuf,
    float* __restrict__ partials, unsigned* __restrict__ bcnt,
    unsigned* __restrict__ gdone, float* __restrict__ out)
{
    const int b = blockIdx.x, s = blockIdx.y, tid = threadIdx.x;
    const int a0 = s * LCH, a1 = a0 + LCH;
    __shared__ float sgb[G * 4], slmk[G * NL * 2], sgz[G * 2];
    __shared__ int slab[G];
    __shared__ int fmap[LCH];
    __shared__ float red[256];
    __shared__ unsigned lhist[NB];
    __shared__ unsigned sc[256];
    __shared__ float accs[8];
    __shared__ int s_last, s_fin, s_t;
    __shared__ unsigned s_kk, s_candN, s_pfx, s_k2;

    for (int i = tid; i < G * 4; i += 256) sgb[i] = gt_boxes[b * G * 4 + i];
    for (int i = tid; i < G * NL * 2; i += 256) slmk[i] = gt_lmk[b * G * NL * 2 + i];
    for (int i = tid; i < G * 2; i += 256) sgz[i] = gt_gaze[b * G * 2 + i];
    if (tid < G) slab[tid] = gt_labels[b * G + tid];
    for (int i = tid; i < LCH; i += 256) fmap[i] = -1;
    for (int i = tid; i < NB; i += 256) lhist[i] = 0;
    __syncthreads();
    if (tid < G && slab[tid] > 0) {
        unsigned long long kb = gbest[b * G + tid];
        if (kb != 0ULL) {
            unsigned a = 0xFFFFFFFFu - (unsigned)(kb & 0xFFFFFFFFu);
            if ((int)a >= a0 && (int)a < a1)
                atomicMax(&fmap[a - a0], tid);   // max g = last-wins
        }
    }
    __syncthreads();

    const signed char* mrow = matches + (size_t)b * A;
    const float* lrow = cls_logits + (size_t)b * A * NC;
    unsigned* krow = negkey + (size_t)b * A;

    // ---- Phase A: loss chunk ----
    float pos_sum = 0, box_sum = 0, lmk_sum = 0, gaze_sum = 0;
    float pos_cnt = 0, face_cnt = 0;

    for (int a = a0 + tid; a < a1; a += 256) {
        int v = mrow[a];
        if (v < 0) v = fmap[a - a0];     // forced overlay
        float x0 = lrow[a * 2], x1 = lrow[a * 2 + 1];
        float mx = fmaxf(x0, x1);
        float lse = mx + logf(expf(x0 - mx) + expf(x1 - mx));
        unsigned key = 0;
        if (v < 0) {
            float closs = lse - x0;   // label 0
            unsigned bits = __float_as_uint(closs);
            key = bits ^ ((bits & 0x80000000u) ? 0xFFFFFFFFu : 0x80000000u);
            int bin = (int)(closs * BSCALE);
            bin = bin < 0 ? 0 : (bin > NB - 1 ? NB - 1 : bin);
            atomicAdd(&lhist[bin], 1u);
        } else {
            int m = v;
            int lab = slab[m];
            float xc = (lab >= 1) ? x1 : x0;   // NC==2
            pos_sum += lse - xc;
            pos_cnt += 1.0f;
            float4 an = *(const float4*)(anchors + a * 4);
            float dcx = an.x, dcy = an.y, dw = an.z, dh = an.w;
            float bx0 = sgb[m * 4], by0 = sgb[m * 4 + 1];
            float bx1 = sgb[m * 4 + 2], by1 = sgb[m * 4 + 3];
            float gcx = (bx0 + bx1) * 0.5f, gcy = (by0 + by1) * 0.5f;
            float gw = bx1 - bx0, gh = by1 - by0;
            float off0 = ((gcx - dcx) / dw) / VAR_C;
            float off1 = ((gcy - dcy) / dh) / VAR_C;
            float off2 = logf(fmaxf(gw / dw, 1e-6f)) / VAR_S;
            float off3 = logf(fmaxf(gh / dh, 1e-6f)) / VAR_S;
            float4 bp = *(const float4*)(box_preds + ((size_t)b * A + a) * 4);
            box_sum += sl1(bp.x - off0) + sl1(bp.y - off1) +
                       sl1(bp.z - off2) + sl1(bp.w - off3);
            if (lab == 1) {  // FACE
                face_cnt += 1.0f;
                const float* lp = lmk_preds + ((size_t)b * A + a) * (NL * 2);
                #pragma unroll
                for (int i = 0; i < NL; ++i) {
                    float tx = ((slmk[m * NL * 2 + 2 * i] - dcx) / dw) / VAR_C;
                    float ty = ((slmk[m * NL * 2 + 2 * i + 1] - dcy) / dh) / VAR_C;
                    lmk_sum += sl1(lp[2 * i] - tx) + sl1(lp[2 * i + 1] - ty);
                }
                const float* gp = gaze_preds + ((size_t)b * A + a) * 2;
                gaze_sum += sl1(gp[0] - sgz[m * 2]) + sl1(gp[1] - sgz[m * 2 + 1]);
            }
        }
        krow[a] = key;
    }

    auto redf = [&](float v) -> float {
        red[tid] = v; __syncthreads();
        for (int st = 128; st > 0; st >>= 1) {
            if (tid < st) red[tid] += red[tid + st];
            __syncthreads();
        }
        float r = red[0]; __syncthreads();
        return r;
    };
    float f0 = redf(pos_sum), f1 = redf(box_sum), f2 = redf(lmk_sum);
    float f3 = redf(gaze_sum), f4 = redf(pos_cnt), f5 = redf(face_cnt);
    if (tid == 0) {
        float* pr = psplit + (b * LSPLIT + s) * PF;
        pr[0] = f0; pr[1] = f1; pr[2] = f2; pr[3] = f3; pr[4] = f4; pr[5] = f5;
    }
    // merge per-block neg hist into ghist[b] (skip zero bins)
    for (int i = tid; i < NB; i += 256) {
        unsigned c = lhist[i];
        if (c) atomicAdd(&ghist[b * NB + i], c);
    }

    // ---- arrival: last block of this batch proceeds to select ----
    __threadfence();
    __syncthreads();
    if (tid == 0) {
        unsigned r = atomicAdd(&bcnt[b], 1u);
        s_last = (r == LSPLIT - 1);
    }
    __syncthreads();
    if (!s_last) return;
    __threadfence();   // acquire: siblings' negkey/ghist/psplit now visible

    // ---- Phase B: per-batch select ----
    if (tid < 6) {
        float v = 0;
        for (int s2 = 0; s2 < LSPLIT; ++s2) v += psplit[(b * LSPLIT + s2) * PF + tid];
        accs[tid] = v;
    }
    for (int i = tid; i < NB; i += 256) lhist[i] = ghist[b * NB + i];
    if (tid == 0) s_candN = 0;
    __syncthreads();

    unsigned pos_t = (unsigned)accs[4];
    unsigned face_t = (unsigned)accs[5];
    unsigned num_pos = pos_t > 1u ? pos_t : 1u;
    unsigned neg_cnt = (unsigned)A - pos_t;
    unsigned k = 3u * num_pos; if (neg_cnt < k) k = neg_cnt;

    // parallel threshold find over NB bins (8 bins per thread)
    {
        unsigned c = 0;
        #pragma unroll
        for (int j = 0; j < 8; ++j) c += lhist[tid * 8 + j];
        sc[tid] = c; __syncthreads();
        for (int off = 1; off < 256; off <<= 1) {
            unsigned add = (tid + off < 256) ? sc[tid + off] : 0u;
            __syncthreads();
            sc[tid] += add;
            __syncthreads();
        }
        unsigned excl = sc[tid] - c;
        if (excl < k && excl + c >= k) {      // unique owner
            unsigned cum = excl;
            #pragma unroll
            for (int j = 7; j >= 0; --j) {
                unsigned h = lhist[tid * 8 + j];
                if (cum + h >= k) { s_t = tid * 8 + j; s_kk = k - cum; break; }
                cum += h;
            }
        }
        __syncthreads();
    }
    const int t = s_t;
    const unsigned kk_bin = s_kk;

    const uint4* krow4 = (const uint4*)krow;
    unsigned* cand = candbuf + (size_t)b * CANDCAP;

    // fused scan: sum bins>t, compact bin==t
    float nsum_top = 0.0f;
    for (int i = tid; i < A / 4; i += 256) {
        uint4 kv = krow4[i];
        #pragma unroll
        for (int j = 0; j < 4; ++j) {
            unsigned key = (&kv.x)[j];
            if (key != 0u) {
                float closs = __uint_as_float(key ^ 0x80000000u);
                int bin = (int)(closs * BSCALE);
                bin = bin < 0 ? 0 : (bin > NB - 1 ? NB - 1 : bin);
                if (bin > t) {
                    nsum_top += closs;
                } else if (bin == t) {
                    unsigned off = atomicAdd(&s_candN, 1u);
                    if (off < CANDCAP) cand[off] = key;
                }
            }
        }
    }
    __syncthreads();
    const unsigned candN = s_candN;
    const bool fast = candN <= CANDCAP;

    // exact radix select of kk_bin-th largest within bin t
    unsigned pfx = 0, kk = kk_bin;
    for (int p = 0; p < 4; ++p) {
        lhist[tid] = 0;
        __syncthreads();
        const int shift = 24 - 8 * p;
        if (fast) {
            for (unsigned i = tid; i < candN; i += 256) {
                unsigned key = cand[i];
                if (p == 0 || (key >> (shift + 8)) == pfx)
                    atomicAdd(&lhist[(key >> shift) & 0xFFu], 1u);
            }
        } else {
            for (int a = tid; a < A; a += 256) {
                unsigned key = krow[a];
                if (key != 0u) {
                    float closs = __uint_as_float(key ^ 0x80000000u);
                    int bin = (int)(closs * BSCALE);
                    bin = bin < 0 ? 0 : (bin > NB - 1 ? NB - 1 : bin);
                    if (bin == t && (p == 0 || (key >> (shift + 8)) == pfx))
                        atomicAdd(&lhist[(key >> shift) & 0xFFu], 1u);
                }
            }
        }
        __syncthreads();
        unsigned c = lhist[tid];
        sc[tid] = c; __syncthreads();
        for (int off = 1; off < 256; off <<= 1) {
            unsigned add = (tid + off < 256) ? sc[tid + off] : 0u;
            __syncthreads();
            sc[tid] += add;
            __syncthreads();
        }
        unsigned excl = sc[tid] - c;
        if (excl < kk && excl + c >= kk) {   // unique owner
            s_pfx = (pfx << 8) | (unsigned)tid;
            s_k2 = kk - excl;
        }
        __syncthreads();
        pfx = s_pfx; kk = s_k2;
        __syncthreads();
    }
    const unsigned Tkey = pfx;
    const unsigned krem = kk;
    const float Tval = __uint_as_float(Tkey ^ 0x80000000u);

    // candidate sum (key > Tkey within bin t)
    float csum = 0.0f;
    if (fast) {
        for (unsigned i = tid; i < candN; i += 256) {
            unsigned key = cand[i];
            if (key > Tkey) csum += __uint_as_float(key ^ 0x80000000u);
        }
    } else {
        for (int a = tid; a < A; a += 256) {
            unsigned key = krow[a];
            if (key != 0u) {
                float closs = __uint_as_float(key ^ 0x80000000u);
                int bin = (int)(closs * BSCALE);
                bin = bin < 0 ? 0 : (bin > NB - 1 ? NB - 1 : bin);
                if (bin == t && key > Tkey) csum += closs;
            }
        }
    }
    red[tid] = nsum_top + csum; __syncthreads();
    for (int st = 128; st > 0; st >>= 1) {
        if (tid < st) red[tid] += red[tid + st];
        __syncthreads();
    }
    if (tid == 0) {
        float* pr = partials + b * PF;
        pr[0] = accs[0]; pr[1] = accs[1]; pr[2] = accs[2]; pr[3] = accs[3];
        pr[4] = red[0] + (float)krem * Tval;
        pr[5] = (float)num_pos;
        pr[6] = (float)(face_t > 1u ? face_t : 1u);
    }

    // ---- arrival: last batch's selector finalizes ----
    __threadfence();
    __syncthreads();
    if (tid == 0) {
        unsigned r2 = atomicAdd(gdone, 1u);
        s_fin = (r2 == B - 1);
    }
    __syncthreads();
    if (!s_fin) return;
    __threadfence();   // acquire: all partials visible

    // ---- Phase C: finalize ----
    if (tid < 64) {
        int tt = tid;
        float ps = partials[tt * PF + 0], bs = partials[tt * PF + 1];
        float ls = partials[tt * PF + 2], gs = partials[tt * PF + 3];
        float ns = partials[tt * PF + 4], npos = partials[tt * PF + 5];
        float nf = partials[tt * PF + 6];
        for (int o = 32; o > 0; o >>= 1) {
            ps += __shfl_down(ps, o); bs += __shfl_down(bs, o);
            ls += __shfl_down(ls, o); gs += __shfl_down(gs, o);
            ns += __shfl_down(ns, o); npos += __shfl_down(npos, o);
            nf += __shfl_down(nf, o);
        }
        if (tt == 0) {
            float tc = (ps + ns) / npos;
            float tb = bs / npos;
            float tl = ls / nf;
            float tg = gs / nf;
            out[0] = tc + 1.0f * tb + 0.5f * tl + 1.0f * tg;
            out[1] = tc; out[2] = tb; out[3] = tl; out[4] = tg;
        }
    }
}

extern "C" void kernel_launch(void* const* d_in, const int* in_sizes, int n_in,
                              void* d_out, int out_size, void* d_ws, size_t ws_size,
                              hipStream_t stream) {
    const float* cls_logits = (const float*)d_in[0];
    const float* box_preds  = (const float*)d_in[1];
    const float* lmk_preds  = (const float*)d_in[2];
    const float* gaze_preds = (const float*)d_in[3];
    const float* anchors    = (const float*)d_in[4];
    const float* gt_boxes   = (const float*)d_in[5];
    const int*   gt_labels  = (const int*)d_in[6];
    const float* gt_lmk     = (const float*)d_in[7];
    const float* gt_gaze    = (const float*)d_in[8];

    char* ws = (char*)d_ws;
    signed char* matches = (signed char*)ws;             ws += (size_t)B * A;              // 1.6 MB
    unsigned* negkey = (unsigned*)ws;                    ws += (size_t)B * A * 4;          // 6.5 MB
    unsigned* candbuf = (unsigned*)ws;                   ws += (size_t)B * CANDCAP * 4;    // 2 MB
    float* psplit = (float*)ws;                          ws += (size_t)B * LSPLIT * PF * 4;
    float* partials = (float*)ws;                        ws += (size_t)B * PF * 4;
    // contiguous zero region:
    unsigned long long* gbest = (unsigned long long*)ws; ws += (size_t)B * G * 8;          // 16 KB
    unsigned* ghist = (unsigned*)ws;                     ws += (size_t)B * NB * 4;         // 512 KB
    unsigned* bcnt = (unsigned*)ws;                      ws += (size_t)B * 4;
    unsigned* gdone = (unsigned*)ws;                     ws += 4;
    float* out = (float*)d_out;

    const int nzero = B * G * 2 + B * NB + B + 1;   // u32 count of zero region
    hipLaunchKernelGGL(init_kernel, dim3((nzero + 255) / 256), dim3(256), 0, stream,
                       (unsigned*)gbest, nzero);
    hipLaunchKernelGGL(match_kernel, dim3(B, MSPLIT), dim3(256), 0, stream,
                       anchors, gt_boxes, gt_labels, matches, gbest);
    hipLaunchKernelGGL(loss_select_kernel, dim3(B, LSPLIT), dim3(256), 0, stream,
                       cls_logits, box_preds, lmk_preds, gaze_preds, anchors,
                       gt_boxes, gt_labels, gt_lmk, gt_gaze, matches, gbest,
                       negkey, ghist, psplit, candbuf, partials, bcnt, gdone, out);
}

// Round 8
// 66.119 us; speedup vs baseline: 1.9749x; 1.9749x over previous
//
#include <hip/hip_runtime.h>
#include <stdint.h>

#define B 64
#define G 32
#define A 25600
#define NC 2
#define NL 5
#define IOU_T 0.5f
#define VAR_C 0.1f
#define VAR_S 0.2f

#define MSPLIT 50
#define MCH (A / MSPLIT)    // 512 anchors per match block, 2 per thread
#define LSPLIT 16
#define LCH (A / LSPLIT)    // 1600 anchors per loss block
#define PF 8                // fields per psplit record

#define NB 2048             // value-histogram bins
#define BSCALE 100.0f       // bin = int(closs * 100), clamped
#define CANDCAP 8192        // per-batch candidate buffer capacity
#define ST 512              // select_kernel threads

__device__ __forceinline__ float sl1(float x) {
    float ax = fabsf(x);
    return ax < 1.0f ? 0.5f * ax * ax : ax - 0.5f;
}

// ---------------------------------------------------------------------------
// K0: zero the per-gt best-anchor table.
// ---------------------------------------------------------------------------
__global__ void init_kernel(unsigned long long* __restrict__ gbest) {
    int i = blockIdx.x * blockDim.x + threadIdx.x;
    if (i < B * G) gbest[i] = 0ULL;
}

// ---------------------------------------------------------------------------
// K1: grid (B, MSPLIT) x 256, 2 anchors per thread.
//  - valid gts compacted (ballot prefix); gt box = one ds_read_b128 broadcast
//  - per-anchor argmax in registers -> matches[b][a]
//  - per-gt best anchor: combine 2 keys, wave shfl max reduce, <=1 LDS atomic
//    per (wave,gt), skipped when no lane intersects; 1 global atomicMax/(blk,gt).
// ---------------------------------------------------------------------------
__global__ __launch_bounds__(256) void match_kernel(
    const float* __restrict__ anchors, const float* __restrict__ gt_boxes,
    const int* __restrict__ gt_labels, signed char* __restrict__ matches,
    unsigned long long* __restrict__ gbest)
{
    const int b = blockIdx.x, s = blockIdx.y, tid = threadIdx.x;
    const int lane = tid & 63;
    __shared__ float4 sbox[G];
    __shared__ int sgorig[G];
    __shared__ unsigned long long sbest[G];
    __shared__ int s_nv;

    if (tid < G) {
        sbest[tid] = 0ULL;
        int valid = gt_labels[b * G + tid] > 0;
        unsigned long long mask = __ballot(valid);
        int pfx = __popcll(mask & ((1ULL << tid) - 1ULL));
        if (valid) {
            sbox[pfx] = *(const float4*)(gt_boxes + (b * G + tid) * 4);
            sgorig[pfx] = tid;
        }
        if (tid == 0) s_nv = (int)__popcll(mask);
    }
    __syncthreads();
    const int nv = s_nv;

    signed char* mrow = matches + (size_t)b * A;
    const int a0 = s * MCH;
    const int aL = a0 + tid, aH = aL + 256;

    float4 anL = *(const float4*)(anchors + aL * 4);
    float4 anH = *(const float4*)(anchors + aH * 4);
    float axL0 = anL.x - anL.z * 0.5f, ayL0 = anL.y - anL.w * 0.5f;
    float axL1 = anL.x + anL.z * 0.5f, ayL1 = anL.y + anL.w * 0.5f;
    float aaL = (axL1 - axL0) * (ayL1 - ayL0);   // mirror reference float path
    float axH0 = anH.x - anH.z * 0.5f, ayH0 = anH.y - anH.w * 0.5f;
    float axH1 = anH.x + anH.z * 0.5f, ayH1 = anH.y + anH.w * 0.5f;
    float aaH = (axH1 - axH0) * (ayH1 - ayH0);

    float bestL = -2.0f, bestH = -2.0f;
    int bciL = 0, bciH = 0;
    for (int ci = 0; ci < nv; ++ci) {
        float4 bb = sbox[ci];                       // one broadcast ds_read_b128
        float area = (bb.z - bb.x) * (bb.w - bb.y); // reference formula
        float iwL = fmaxf(fminf(bb.z, axL1) - fmaxf(bb.x, axL0), 0.0f);
        float ihL = fmaxf(fminf(bb.w, ayL1) - fmaxf(bb.y, ayL0), 0.0f);
        float interL = iwL * ihL;
        float iwH = fmaxf(fminf(bb.z, axH1) - fmaxf(bb.x, axH0), 0.0f);
        float ihH = fmaxf(fminf(bb.w, ayH1) - fmaxf(bb.y, ayH0), 0.0f);
        float interH = iwH * ihH;
        float iouL = 0.0f, iouH = 0.0f;             // exact: 0/den == +0.0
        if (__any(interL > 0.0f || interH > 0.0f)) { // wave-uniform skip
            iouL = interL / (area + aaL - interL + 1e-9f);
            iouH = interH / (area + aaH - interH + 1e-9f);
            unsigned long long keyL =
                ((unsigned long long)__float_as_uint(iouL) << 32) |
                (unsigned)(0xFFFFFFFFu - (unsigned)aL);
            unsigned long long keyH =
                ((unsigned long long)__float_as_uint(iouH) << 32) |
                (unsigned)(0xFFFFFFFFu - (unsigned)aH);
            unsigned long long km = keyL > keyH ? keyL : keyH;
            #pragma unroll
            for (int off = 32; off > 0; off >>= 1) {
                unsigned long long o = __shfl_down(km, off);
                if (o > km) km = o;
            }
            if (lane == 0 && km > sbest[ci]) atomicMax(&sbest[ci], km);
        }
        if (iouL > bestL) { bestL = iouL; bciL = ci; }  // first-max wins
        if (iouH > bestH) { bestH = iouH; bciH = ci; }
    }
    mrow[aL] = (bestL >= IOU_T) ? (signed char)sgorig[bciL] : (signed char)(-1);
    mrow[aH] = (bestH >= IOU_T) ? (signed char)sgorig[bciH] : (signed char)(-1);
    __syncthreads();
    if (tid < nv && sbest[tid] != 0ULL)
        atomicMax(&gbest[b * G + sgorig[tid]], sbest[tid]);
}

// ---------------------------------------------------------------------------
// K2: positive-side partial sums per (b, split) + negative-loss keys + per-
// block 2048-bin negative hist (plain coalesced store, NO global atomics).
// grid (B, LSPLIT) x 256.  Forced matches via gbest overlay.
// ---------------------------------------------------------------------------
__global__ __launch_bounds__(256) void loss_split_kernel(
    const float* __restrict__ cls_logits, const float* __restrict__ box_preds,
    const float* __restrict__ lmk_preds, const float* __restrict__ gaze_preds,
    const float* __restrict__ anchors, const float* __restrict__ gt_boxes,
    const int* __restrict__ gt_labels, const float* __restrict__ gt_lmk,
    const float* __restrict__ gt_gaze, const signed char* __restrict__ matches,
    const unsigned long long* __restrict__ gbest,
    unsigned* __restrict__ negkey, unsigned* __restrict__ bhist,
    float* __restrict__ psplit)
{
    const int b = blockIdx.x, s = blockIdx.y, tid = threadIdx.x;
    const int a0 = s * LCH, a1 = a0 + LCH;
    __shared__ float sgb[G * 4], slmk[G * NL * 2], sgz[G * 2];
    __shared__ int slab[G];
    __shared__ int fmap[LCH];           // forced overlay: -1 or g
    __shared__ float red[256];
    __shared__ unsigned lhist[NB];

    for (int i = tid; i < G * 4; i += 256) sgb[i] = gt_boxes[b * G * 4 + i];
    for (int i = tid; i < G * NL * 2; i += 256) slmk[i] = gt_lmk[b * G * NL * 2 + i];
    for (int i = tid; i < G * 2; i += 256) sgz[i] = gt_gaze[b * G * 2 + i];
    if (tid < G) slab[tid] = gt_labels[b * G + tid];
    for (int i = tid; i < LCH; i += 256) fmap[i] = -1;
    for (int i = tid; i < NB; i += 256) lhist[i] = 0;
    __syncthreads();
    if (tid < G && slab[tid] > 0) {
        unsigned long long kb = gbest[b * G + tid];
        if (kb != 0ULL) {
            unsigned a = 0xFFFFFFFFu - (unsigned)(kb & 0xFFFFFFFFu);
            if ((int)a >= a0 && (int)a < a1)
                atomicMax(&fmap[a - a0], tid);   // max g = last-wins
        }
    }
    __syncthreads();

    const signed char* mrow = matches + (size_t)b * A;
    const float* lrow = cls_logits + (size_t)b * A * NC;
    unsigned* krow = negkey + (size_t)b * A;

    float pos_sum = 0, box_sum = 0, lmk_sum = 0, gaze_sum = 0;
    float pos_cnt = 0, face_cnt = 0;

    for (int a = a0 + tid; a < a1; a += 256) {
        int v = mrow[a];
        if (v < 0) v = fmap[a - a0];     // forced overlay (still -1 if none)
        float2 xl = *(const float2*)(lrow + a * 2);
        float x0 = xl.x, x1 = xl.y;
        float mx = fmaxf(x0, x1);
        float lse = mx + logf(expf(x0 - mx) + expf(x1 - mx));
        unsigned key = 0;
        if (v < 0) {
            float closs = lse - x0;   // label 0; closs >= 0 always
            unsigned bits = __float_as_uint(closs);
            key = bits ^ ((bits & 0x80000000u) ? 0xFFFFFFFFu : 0x80000000u);
            int bin = (int)(closs * BSCALE);
            bin = bin < 0 ? 0 : (bin > NB - 1 ? NB - 1 : bin);
            atomicAdd(&lhist[bin], 1u);
        } else {
            int m = v;
            int lab = slab[m];
            float xc = (lab >= 1) ? x1 : x0;   // NC==2
            pos_sum += lse - xc;
            pos_cnt += 1.0f;
            float4 an = *(const float4*)(anchors + a * 4);
            float dcx = an.x, dcy = an.y, dw = an.z, dh = an.w;
            float bx0 = sgb[m * 4], by0 = sgb[m * 4 + 1];
            float bx1 = sgb[m * 4 + 2], by1 = sgb[m * 4 + 3];
            float gcx = (bx0 + bx1) * 0.5f, gcy = (by0 + by1) * 0.5f;
            float gw = bx1 - bx0, gh = by1 - by0;
            float off0 = ((gcx - dcx) / dw) / VAR_C;
            float off1 = ((gcy - dcy) / dh) / VAR_C;
            float off2 = logf(fmaxf(gw / dw, 1e-6f)) / VAR_S;
            float off3 = logf(fmaxf(gh / dh, 1e-6f)) / VAR_S;
            float4 bp = *(const float4*)(box_preds + ((size_t)b * A + a) * 4);
            box_sum += sl1(bp.x - off0) + sl1(bp.y - off1) +
                       sl1(bp.z - off2) + sl1(bp.w - off3);
            if (lab == 1) {  // FACE
                face_cnt += 1.0f;
                const float* lp = lmk_preds + ((size_t)b * A + a) * (NL * 2);
                #pragma unroll
                for (int i = 0; i < NL; ++i) {
                    float tx = ((slmk[m * NL * 2 + 2 * i] - dcx) / dw) / VAR_C;
                    float ty = ((slmk[m * NL * 2 + 2 * i + 1] - dcy) / dh) / VAR_C;
                    lmk_sum += sl1(lp[2 * i] - tx) + sl1(lp[2 * i + 1] - ty);
                }
                const float* gp = gaze_preds + ((size_t)b * A + a) * 2;
                gaze_sum += sl1(gp[0] - sgz[m * 2]) + sl1(gp[1] - sgz[m * 2 + 1]);
            }
        }
        krow[a] = key;
    }

    auto redf = [&](float v) -> float {
        red[tid] = v; __syncthreads();
        for (int st = 128; st > 0; st >>= 1) {
            if (tid < st) red[tid] += red[tid + st];
            __syncthreads();
        }
        float r = red[0]; __syncthreads();
        return r;
    };
    float f0 = redf(pos_sum), f1 = redf(box_sum), f2 = redf(lmk_sum);
    float f3 = redf(gaze_sum), f4 = redf(pos_cnt), f5 = redf(face_cnt);
    if (tid == 0) {
        float* pr = psplit + (b * LSPLIT + s) * PF;
        pr[0] = f0; pr[1] = f1; pr[2] = f2; pr[3] = f3; pr[4] = f4; pr[5] = f5;
    }
    // store per-block hist (coalesced, full overwrite)
    unsigned* hrow = bhist + ((size_t)b * LSPLIT + s) * NB;
    for (int i = tid; i < NB; i += 256) hrow[i] = lhist[i];
}

// ---------------------------------------------------------------------------
// K3: per-batch top-k negative sum. grid B x 512.  Histogram comes pre-built
// from loss_split (sum of 16 per-block hists); one negkey scan + cand radix.
// ---------------------------------------------------------------------------
__global__ __launch_bounds__(ST) void select_kernel(
    const unsigned* __restrict__ negkey, const unsigned* __restrict__ bhist,
    const float* __restrict__ psplit, unsigned* __restrict__ candbuf,
    float* __restrict__ partials)
{
    const int b = blockIdx.x, tid = threadIdx.x;
    __shared__ unsigned lhist[NB];
    __shared__ unsigned sc[ST];
    __shared__ float red[ST];
    __shared__ float accs[8];
    __shared__ int s_t;
    __shared__ unsigned s_kk;
    __shared__ unsigned s_candN;
    __shared__ unsigned s_pfx, s_k2;

    const unsigned* krow = negkey + (size_t)b * A;
    const uint4* krow4 = (const uint4*)krow;
    unsigned* cand = candbuf + (size_t)b * CANDCAP;

    if (tid < 6) {
        float v = 0;
        for (int s2 = 0; s2 < LSPLIT; ++s2) v += psplit[(b * LSPLIT + s2) * PF + tid];
        accs[tid] = v;
    }
    // sum the 16 per-block hists (coalesced)
    for (int i = tid; i < NB; i += ST) {
        unsigned v = 0;
        const unsigned* hb = bhist + (size_t)b * LSPLIT * NB + i;
        #pragma unroll
        for (int s2 = 0; s2 < LSPLIT; ++s2) v += hb[s2 * NB];
        lhist[i] = v;
    }
    if (tid == 0) s_candN = 0;
    __syncthreads();

    unsigned pos_t = (unsigned)accs[4];
    unsigned face_t = (unsigned)accs[5];
    unsigned num_pos = pos_t > 1u ? pos_t : 1u;
    unsigned neg_cnt = (unsigned)A - pos_t;
    unsigned k = 3u * num_pos; if (neg_cnt < k) k = neg_cnt;

    // ---- parallel threshold find over NB bins (4 bins per thread) ----
    {
        unsigned c = lhist[tid * 4] + lhist[tid * 4 + 1] +
                     lhist[tid * 4 + 2] + lhist[tid * 4 + 3];
        sc[tid] = c; __syncthreads();
        #pragma unroll
        for (int off = 1; off < ST; off <<= 1) {
            unsigned add = (tid + off < ST) ? sc[tid + off] : 0u;
            __syncthreads();
            sc[tid] += add;
            __syncthreads();
        }
        unsigned excl = sc[tid] - c;          // count in strictly higher chunks
        if (excl < k && excl + c >= k) {      // unique owner
            unsigned cum = excl;
            #pragma unroll
            for (int j = 3; j >= 0; --j) {
                unsigned h = lhist[tid * 4 + j];
                if (cum + h >= k) { s_t = tid * 4 + j; s_kk = k - cum; break; }
                cum += h;
            }
        }
        __syncthreads();
    }
    const int t = s_t;
    const unsigned kk_bin = s_kk;

    // ---- single scan: sum bins>t, compact bin==t candidates ----
    float nsum_top = 0.0f;
    for (int i = tid; i < A / 4; i += ST) {
        uint4 kv = krow4[i];
        #pragma unroll
        for (int j = 0; j < 4; ++j) {
            unsigned key = (&kv.x)[j];
            if (key != 0u) {
                float closs = __uint_as_float(key ^ 0x80000000u);
                int bin = (int)(closs * BSCALE);
                bin = bin < 0 ? 0 : (bin > NB - 1 ? NB - 1 : bin);
                if (bin > t) {
                    nsum_top += closs;
                } else if (bin == t) {
                    unsigned off = atomicAdd(&s_candN, 1u);
                    if (off < CANDCAP) cand[off] = key;
                }
            }
        }
    }
    __syncthreads();
    const unsigned candN = s_candN;
    const bool fast = candN <= CANDCAP;

    // ---- exact radix select of kk_bin-th largest within bin t ----
    unsigned pfx = 0, kk = kk_bin;
    for (int p = 0; p < 4; ++p) {
        if (tid < 256) lhist[tid] = 0;
        __syncthreads();
        const int shift = 24 - 8 * p;
        if (fast) {
            for (unsigned i = tid; i < candN; i += ST) {
                unsigned key = cand[i];
                if (p == 0 || (key >> (shift + 8)) == pfx)
                    atomicAdd(&lhist[(key >> shift) & 0xFFu], 1u);
            }
        } else {   // overflow fallback: scan full row with bin filter
            for (int a = tid; a < A; a += ST) {
                unsigned key = krow[a];
                if (key != 0u) {
                    float closs = __uint_as_float(key ^ 0x80000000u);
                    int bin = (int)(closs * BSCALE);
                    bin = bin < 0 ? 0 : (bin > NB - 1 ? NB - 1 : bin);
                    if (bin == t && (p == 0 || (key >> (shift + 8)) == pfx))
                        atomicAdd(&lhist[(key >> shift) & 0xFFu], 1u);
                }
            }
        }
        __syncthreads();
        // parallel suffix scan over 256 radix bins
        unsigned c = (tid < 256) ? lhist[tid] : 0u;
        sc[tid] = c; __syncthreads();
        #pragma unroll
        for (int off = 1; off < ST; off <<= 1) {
            unsigned add = (tid + off < ST) ? sc[tid + off] : 0u;
            __syncthreads();
            sc[tid] += add;
            __syncthreads();
        }
        if (tid < 256) {
            unsigned excl = sc[tid] - c;
            if (excl < kk && excl + c >= kk) {   // unique owner
                s_pfx = (pfx << 8) | (unsigned)tid;
                s_k2 = kk - excl;
            }
        }
        __syncthreads();
        pfx = s_pfx; kk = s_k2;
        __syncthreads();
    }
    const unsigned Tkey = pfx;
    const unsigned krem = kk;
    const float Tval = __uint_as_float(Tkey ^ 0x80000000u);

    // ---- candidate sum (key > Tkey within bin t) ----
    float csum = 0.0f;
    if (fast) {
        for (unsigned i = tid; i < candN; i += ST) {
            unsigned key = cand[i];
            if (key > Tkey) csum += __uint_as_float(key ^ 0x80000000u);
        }
    } else {
        for (int a = tid; a < A; a += ST) {
            unsigned key = krow[a];
            if (key != 0u) {
                float closs = __uint_as_float(key ^ 0x80000000u);
                int bin = (int)(closs * BSCALE);
                bin = bin < 0 ? 0 : (bin > NB - 1 ? NB - 1 : bin);
                if (bin == t && key > Tkey) csum += closs;
            }
        }
    }
    red[tid] = nsum_top + csum; __syncthreads();
    for (int st = ST / 2; st > 0; st >>= 1) {
        if (tid < st) red[tid] += red[tid + st];
        __syncthreads();
    }
    if (tid == 0) {
        float* pr = partials + b * PF;
        pr[0] = accs[0]; pr[1] = accs[1]; pr[2] = accs[2]; pr[3] = accs[3];
        pr[4] = red[0] + (float)krem * Tval;
        pr[5] = (float)num_pos;
        pr[6] = (float)(face_t > 1u ? face_t : 1u);
    }
}

// ---------------------------------------------------------------------------
// K4: combine per-batch partials -> 5 scalar outputs.
// ---------------------------------------------------------------------------
__global__ void finalize_kernel(const float* __restrict__ partials,
                                float* __restrict__ out)
{
    int t = threadIdx.x;  // 64 threads = 1 wave
    float ps = partials[t * PF + 0], bs = partials[t * PF + 1];
    float ls = partials[t * PF + 2], gs = partials[t * PF + 3];
    float ns = partials[t * PF + 4], npos = partials[t * PF + 5];
    float nf = partials[t * PF + 6];
    for (int o = 32; o > 0; o >>= 1) {
        ps += __shfl_down(ps, o); bs += __shfl_down(bs, o);
        ls += __shfl_down(ls, o); gs += __shfl_down(gs, o);
        ns += __shfl_down(ns, o); npos += __shfl_down(npos, o);
        nf += __shfl_down(nf, o);
    }
    if (t == 0) {
        float tc = (ps + ns) / npos;
        float tb = bs / npos;
        float tl = ls / nf;
        float tg = gs / nf;
        out[0] = tc + 1.0f * tb + 0.5f * tl + 1.0f * tg;
        out[1] = tc; out[2] = tb; out[3] = tl; out[4] = tg;
    }
}

extern "C" void kernel_launch(void* const* d_in, const int* in_sizes, int n_in,
                              void* d_out, int out_size, void* d_ws, size_t ws_size,
                              hipStream_t stream) {
    const float* cls_logits = (const float*)d_in[0];
    const float* box_preds  = (const float*)d_in[1];
    const float* lmk_preds  = (const float*)d_in[2];
    const float* gaze_preds = (const float*)d_in[3];
    const float* anchors    = (const float*)d_in[4];
    const float* gt_boxes   = (const float*)d_in[5];
    const int*   gt_labels  = (const int*)d_in[6];
    const float* gt_lmk     = (const float*)d_in[7];
    const float* gt_gaze    = (const float*)d_in[8];

    char* ws = (char*)d_ws;
    signed char* matches = (signed char*)ws;             ws += (size_t)B * A;              // 1.6 MB
    unsigned long long* gbest = (unsigned long long*)ws; ws += (size_t)B * G * 8;          // 16 KB
    unsigned* negkey = (unsigned*)ws;                    ws += (size_t)B * A * 4;          // 6.5 MB
    unsigned* bhist = (unsigned*)ws;                     ws += (size_t)B * LSPLIT * NB * 4; // 8 MB
    unsigned* candbuf = (unsigned*)ws;                   ws += (size_t)B * CANDCAP * 4;    // 2 MB
    float* psplit = (float*)ws;                          ws += (size_t)B * LSPLIT * PF * 4;
    float* partials = (float*)ws;
    float* out = (float*)d_out;

    hipLaunchKernelGGL(init_kernel, dim3((B * G + 255) / 256), dim3(256), 0, stream, gbest);
    hipLaunchKernelGGL(match_kernel, dim3(B, MSPLIT), dim3(256), 0, stream,
                       anchors, gt_boxes, gt_labels, matches, gbest);
    hipLaunchKernelGGL(loss_split_kernel, dim3(B, LSPLIT), dim3(256), 0, stream,
                       cls_logits, box_preds, lmk_preds, gaze_preds, anchors,
                       gt_boxes, gt_labels, gt_lmk, gt_gaze, matches, gbest,
                       negkey, bhist, psplit);
    hipLaunchKernelGGL(select_kernel, dim3(B), dim3(ST), 0, stream,
                       negkey, bhist, psplit, candbuf, partials);
    hipLaunchKernelGGL(finalize_kernel, dim3(1), dim3(64), 0, stream,
                       partials, out);
}

// Round 9
// 62.335 us; speedup vs baseline: 2.0948x; 1.0607x over previous
//
#include <hip/hip_runtime.h>
#include <stdint.h>

#define B 64
#define G 32
#define A 25600
#define NC 2
#define NL 5
#define IOU_T 0.5f
#define VAR_C 0.1f
#define VAR_S 0.2f

#define MSPLIT 50
#define MCH (A / MSPLIT)    // 512 anchors per fused block, 2 per thread
#define PF 8                // fields per psplit record

#define NB2 256             // coarse value-histogram bins
#define BSCALE2 20.0f       // bin = int(closs * 20), clamped to 255
#define CANDCAP 8192        // per-batch candidate buffer capacity
#define ST 512              // select_kernel threads

__device__ __forceinline__ float sl1(float x) {
    float ax = fabsf(x);
    return ax < 1.0f ? 0.5f * ax * ax : ax - 0.5f;
}

__device__ __forceinline__ int vbin(float closs) {
    int bin = (int)(closs * BSCALE2);
    return bin < 0 ? 0 : (bin > NB2 - 1 ? NB2 - 1 : bin);
}

// ---------------------------------------------------------------------------
// K0: zero the per-gt best-anchor table.
// ---------------------------------------------------------------------------
__global__ void init_kernel(unsigned long long* __restrict__ gbest) {
    int i = blockIdx.x * blockDim.x + threadIdx.x;
    if (i < B * G) gbest[i] = 0ULL;
}

// ---------------------------------------------------------------------------
// K1 FUSED match+loss: grid (B, MSPLIT) x 256, 2 anchors per thread.
//  - threshold match computed in registers, then IMMEDIATELY consumed by the
//    loss path for the same anchors (no matches round-trip, no 2nd kernel)
//  - negatives: monotonic key -> negkey + 256-bin LDS hist -> bhist record
//  - per-gt best anchor -> gbest atomicMax (forced matches applied in select)
// ---------------------------------------------------------------------------
__global__ __launch_bounds__(256) void fused_kernel(
    const float* __restrict__ cls_logits, const float* __restrict__ box_preds,
    const float* __restrict__ lmk_preds, const float* __restrict__ gaze_preds,
    const float* __restrict__ anchors, const float* __restrict__ gt_boxes,
    const int* __restrict__ gt_labels, const float* __restrict__ gt_lmk,
    const float* __restrict__ gt_gaze, signed char* __restrict__ matches,
    unsigned long long* __restrict__ gbest, unsigned* __restrict__ negkey,
    unsigned* __restrict__ bhist, float* __restrict__ psplit)
{
    const int b = blockIdx.x, s = blockIdx.y, tid = threadIdx.x;
    const int lane = tid & 63;
    __shared__ float4 sbox[G];
    __shared__ int sgorig[G];
    __shared__ unsigned long long sbest[G];
    __shared__ int s_nv;
    __shared__ float sgb[G * 4], slmk[G * NL * 2], sgz[G * 2];
    __shared__ int slab[G];
    __shared__ unsigned lhist[NB2];
    __shared__ float red[256];

    if (tid < G) {
        sbest[tid] = 0ULL;
        int valid = gt_labels[b * G + tid] > 0;
        unsigned long long mask = __ballot(valid);
        int pfx = __popcll(mask & ((1ULL << tid) - 1ULL));
        if (valid) {
            sbox[pfx] = *(const float4*)(gt_boxes + (b * G + tid) * 4);
            sgorig[pfx] = tid;
        }
        if (tid == 0) s_nv = (int)__popcll(mask);
    }
    for (int i = tid; i < G * 4; i += 256) sgb[i] = gt_boxes[b * G * 4 + i];
    for (int i = tid; i < G * NL * 2; i += 256) slmk[i] = gt_lmk[b * G * NL * 2 + i];
    for (int i = tid; i < G * 2; i += 256) sgz[i] = gt_gaze[b * G * 2 + i];
    if (tid < G) slab[tid] = gt_labels[b * G + tid];
    lhist[tid] = 0;
    __syncthreads();
    const int nv = s_nv;

    signed char* mrow = matches + (size_t)b * A;
    const int a0 = s * MCH;
    const int aL = a0 + tid, aH = aL + 256;

    // ---- match phase ----
    float4 anL = *(const float4*)(anchors + aL * 4);
    float4 anH = *(const float4*)(anchors + aH * 4);
    float axL0 = anL.x - anL.z * 0.5f, ayL0 = anL.y - anL.w * 0.5f;
    float axL1 = anL.x + anL.z * 0.5f, ayL1 = anL.y + anL.w * 0.5f;
    float aaL = (axL1 - axL0) * (ayL1 - ayL0);   // mirror reference float path
    float axH0 = anH.x - anH.z * 0.5f, ayH0 = anH.y - anH.w * 0.5f;
    float axH1 = anH.x + anH.z * 0.5f, ayH1 = anH.y + anH.w * 0.5f;
    float aaH = (axH1 - axH0) * (ayH1 - ayH0);

    float bestL = -2.0f, bestH = -2.0f;
    int bciL = 0, bciH = 0;
    for (int ci = 0; ci < nv; ++ci) {
        float4 bb = sbox[ci];                       // broadcast ds_read_b128
        float area = (bb.z - bb.x) * (bb.w - bb.y); // reference formula
        float iwL = fmaxf(fminf(bb.z, axL1) - fmaxf(bb.x, axL0), 0.0f);
        float ihL = fmaxf(fminf(bb.w, ayL1) - fmaxf(bb.y, ayL0), 0.0f);
        float interL = iwL * ihL;
        float iwH = fmaxf(fminf(bb.z, axH1) - fmaxf(bb.x, axH0), 0.0f);
        float ihH = fmaxf(fminf(bb.w, ayH1) - fmaxf(bb.y, ayH0), 0.0f);
        float interH = iwH * ihH;
        float iouL = 0.0f, iouH = 0.0f;             // exact: 0/den == +0.0
        if (__any(interL > 0.0f || interH > 0.0f)) { // wave-uniform skip
            iouL = interL / (area + aaL - interL + 1e-9f);
            iouH = interH / (area + aaH - interH + 1e-9f);
            unsigned long long keyL =
                ((unsigned long long)__float_as_uint(iouL) << 32) |
                (unsigned)(0xFFFFFFFFu - (unsigned)aL);
            unsigned long long keyH =
                ((unsigned long long)__float_as_uint(iouH) << 32) |
                (unsigned)(0xFFFFFFFFu - (unsigned)aH);
            unsigned long long km = keyL > keyH ? keyL : keyH;
            #pragma unroll
            for (int off = 32; off > 0; off >>= 1) {
                unsigned long long o = __shfl_down(km, off);
                if (o > km) km = o;
            }
            if (lane == 0 && km > sbest[ci]) atomicMax(&sbest[ci], km);
        }
        if (iouL > bestL) { bestL = iouL; bciL = ci; }  // first-max wins
        if (iouH > bestH) { bestH = iouH; bciH = ci; }
    }
    const int vL = (bestL >= IOU_T) ? sgorig[bciL] : -1;
    const int vH = (bestH >= IOU_T) ? sgorig[bciH] : -1;
    mrow[aL] = (signed char)vL;
    mrow[aH] = (signed char)vH;

    // ---- loss phase (consumes vL/vH from registers) ----
    const float* lrow = cls_logits + (size_t)b * A * NC;
    unsigned* krow = negkey + (size_t)b * A;

    float pos_sum = 0, box_sum = 0, lmk_sum = 0, gaze_sum = 0;
    float pos_cnt = 0, face_cnt = 0;

    #pragma unroll
    for (int h = 0; h < 2; ++h) {
        const int a = h ? aH : aL;
        const int v = h ? vH : vL;
        const float4 an = h ? anH : anL;
        float2 xl = *(const float2*)(lrow + a * 2);
        float x0 = xl.x, x1 = xl.y;
        float mx = fmaxf(x0, x1);
        float lse = mx + logf(expf(x0 - mx) + expf(x1 - mx));
        unsigned key = 0;
        if (v < 0) {
            float closs = lse - x0;   // label 0; closs > 0
            unsigned bits = __float_as_uint(closs);
            key = bits ^ ((bits & 0x80000000u) ? 0xFFFFFFFFu : 0x80000000u);
            atomicAdd(&lhist[vbin(closs)], 1u);
        } else {
            int m = v;
            int lab = slab[m];
            float xc = (lab >= 1) ? x1 : x0;   // NC==2
            pos_sum += lse - xc;
            pos_cnt += 1.0f;
            float dcx = an.x, dcy = an.y, dw = an.z, dh = an.w;
            float bx0 = sgb[m * 4], by0 = sgb[m * 4 + 1];
            float bx1 = sgb[m * 4 + 2], by1 = sgb[m * 4 + 3];
            float gcx = (bx0 + bx1) * 0.5f, gcy = (by0 + by1) * 0.5f;
            float gw = bx1 - bx0, gh = by1 - by0;
            float off0 = ((gcx - dcx) / dw) / VAR_C;
            float off1 = ((gcy - dcy) / dh) / VAR_C;
            float off2 = logf(fmaxf(gw / dw, 1e-6f)) / VAR_S;
            float off3 = logf(fmaxf(gh / dh, 1e-6f)) / VAR_S;
            float4 bp = *(const float4*)(box_preds + ((size_t)b * A + a) * 4);
            box_sum += sl1(bp.x - off0) + sl1(bp.y - off1) +
                       sl1(bp.z - off2) + sl1(bp.w - off3);
            if (lab == 1) {  // FACE
                face_cnt += 1.0f;
                const float* lp = lmk_preds + ((size_t)b * A + a) * (NL * 2);
                #pragma unroll
                for (int i = 0; i < NL; ++i) {
                    float tx = ((slmk[m * NL * 2 + 2 * i] - dcx) / dw) / VAR_C;
                    float ty = ((slmk[m * NL * 2 + 2 * i + 1] - dcy) / dh) / VAR_C;
                    lmk_sum += sl1(lp[2 * i] - tx) + sl1(lp[2 * i + 1] - ty);
                }
                const float* gp = gaze_preds + ((size_t)b * A + a) * 2;
                gaze_sum += sl1(gp[0] - sgz[m * 2]) + sl1(gp[1] - sgz[m * 2 + 1]);
            }
        }
        krow[a] = key;
    }

    auto redf = [&](float v) -> float {
        red[tid] = v; __syncthreads();
        for (int st = 128; st > 0; st >>= 1) {
            if (tid < st) red[tid] += red[tid + st];
            __syncthreads();
        }
        float r = red[0]; __syncthreads();
        return r;
    };
    float f0 = redf(pos_sum), f1 = redf(box_sum), f2 = redf(lmk_sum);
    float f3 = redf(gaze_sum), f4 = redf(pos_cnt), f5 = redf(face_cnt);
    if (tid == 0) {
        float* pr = psplit + (b * MSPLIT + s) * PF;
        pr[0] = f0; pr[1] = f1; pr[2] = f2; pr[3] = f3; pr[4] = f4; pr[5] = f5;
    }
    bhist[(b * MSPLIT + s) * NB2 + tid] = lhist[tid];   // coalesced store
    if (tid < nv && sbest[tid] != 0ULL)
        atomicMax(&gbest[b * G + sgorig[tid]], sbest[tid]);
}

// ---------------------------------------------------------------------------
// K2 select (+forced-match fixup, +per-batch reduce): grid B x 512.
// Phase 0: merge 50 hists + psplit records.
// Phase 1: FIXUP — lanes 0..31 decode gbest, dedup last-wins via shfl,
//   subtract forced anchors' neg contributions (hist bin, negkey=0) and add
//   their pos contributions. Block-local; no fences.
// Phase 2+: threshold bin (parallel suffix scan), fused sum+compact scan,
//   exact radix over candidates, deterministic sums -> partials[b].
// ---------------------------------------------------------------------------
__global__ __launch_bounds__(ST) void select_kernel(
    const float* __restrict__ cls_logits, const float* __restrict__ box_preds,
    const float* __restrict__ lmk_preds, const float* __restrict__ gaze_preds,
    const float* __restrict__ anchors, const float* __restrict__ gt_boxes,
    const int* __restrict__ gt_labels, const float* __restrict__ gt_lmk,
    const float* __restrict__ gt_gaze, const signed char* __restrict__ matches,
    const unsigned long long* __restrict__ gbest,
    unsigned* __restrict__ negkey, const unsigned* __restrict__ bhist,
    const float* __restrict__ psplit, unsigned* __restrict__ candbuf,
    float* __restrict__ partials)
{
    const int b = blockIdx.x, tid = threadIdx.x;
    __shared__ unsigned lhist[NB2];
    __shared__ unsigned sc[ST];
    __shared__ float red[ST];
    __shared__ float accs[8];
    __shared__ int s_t;
    __shared__ unsigned s_kk, s_candN, s_pfx, s_k2;

    unsigned* krow = negkey + (size_t)b * A;
    const uint4* krow4 = (const uint4*)krow;
    const float* lrow = cls_logits + (size_t)b * A * NC;
    unsigned* cand = candbuf + (size_t)b * CANDCAP;

    // ---- phase 0 ----
    if (tid < 6) {
        float v = 0;
        for (int s2 = 0; s2 < MSPLIT; ++s2) v += psplit[(b * MSPLIT + s2) * PF + tid];
        accs[tid] = v;
    }
    if (tid < NB2) {
        unsigned v = 0;
        const unsigned* hb = bhist + (size_t)b * MSPLIT * NB2 + tid;
        for (int s2 = 0; s2 < MSPLIT; ++s2) v += hb[s2 * NB2];
        lhist[tid] = v;
    }
    if (tid == 0) s_candN = 0;
    __syncthreads();

    // ---- phase 1: fixup (forced matches) ----
    float f0 = 0, f1 = 0, f2 = 0, f3 = 0, f4 = 0, f5 = 0;
    int fbin = -1, fa = -1;
    if (tid < 32) {
        const int g = tid;
        int lab = gt_labels[b * G + g];
        unsigned long long kb = gbest[b * G + g];
        int a_c = -1;
        if (lab > 0 && kb != 0ULL) {
            unsigned a = 0xFFFFFFFFu - (unsigned)(kb & 0xFFFFFFFFu);
            if (matches[(size_t)b * A + a] < 0) a_c = (int)a;   // threshold wins
        }
        bool win = a_c >= 0;
        for (int j = 0; j < 32; ++j) {                 // last-wins dedup
            int aj = __shfl(a_c, j);
            if (j > g && a_c >= 0 && aj == a_c) win = false;
        }
        if (win) {
            const int a = a_c;
            float2 xl = *(const float2*)(lrow + a * 2);
            float x0 = xl.x, x1 = xl.y;
            float mx = fmaxf(x0, x1);
            float lse = mx + logf(expf(x0 - mx) + expf(x1 - mx));
            float xc = (lab >= 1) ? x1 : x0;
            f0 = lse - xc; f4 = 1.0f;
            float4 an = *(const float4*)(anchors + a * 4);
            const float* gb = gt_boxes + (b * G + g) * 4;
            float bx0 = gb[0], by0 = gb[1], bx1 = gb[2], by1 = gb[3];
            float gcx = (bx0 + bx1) * 0.5f, gcy = (by0 + by1) * 0.5f;
            float gw = bx1 - bx0, gh = by1 - by0;
            float off0 = ((gcx - an.x) / an.z) / VAR_C;
            float off1 = ((gcy - an.y) / an.w) / VAR_C;
            float off2 = logf(fmaxf(gw / an.z, 1e-6f)) / VAR_S;
            float off3 = logf(fmaxf(gh / an.w, 1e-6f)) / VAR_S;
            float4 bp = *(const float4*)(box_preds + ((size_t)b * A + a) * 4);
            f1 = sl1(bp.x - off0) + sl1(bp.y - off1) +
                 sl1(bp.z - off2) + sl1(bp.w - off3);
            if (lab == 1) {
                f5 = 1.0f;
                const float* gl = gt_lmk + (b * G + g) * NL * 2;
                const float* lp = lmk_preds + ((size_t)b * A + a) * (NL * 2);
                #pragma unroll
                for (int i = 0; i < NL; ++i) {
                    float tx = ((gl[2 * i] - an.x) / an.z) / VAR_C;
                    float ty = ((gl[2 * i + 1] - an.y) / an.w) / VAR_C;
                    f2 += sl1(lp[2 * i] - tx) + sl1(lp[2 * i + 1] - ty);
                }
                const float* gz = gt_gaze + (b * G + g) * 2;
                const float* gp = gaze_preds + ((size_t)b * A + a) * 2;
                f3 = sl1(gp[0] - gz[0]) + sl1(gp[1] - gz[1]);
            }
            unsigned key = krow[a];
            float closs = __uint_as_float(key ^ 0x80000000u);
            fbin = vbin(closs); fa = a;
        }
    }
    if (tid < 64) {   // whole wave 0 reduces (lanes 32..63 carry zeros)
        #pragma unroll
        for (int off = 16; off > 0; off >>= 1) {
            f0 += __shfl_down(f0, off); f1 += __shfl_down(f1, off);
            f2 += __shfl_down(f2, off); f3 += __shfl_down(f3, off);
            f4 += __shfl_down(f4, off); f5 += __shfl_down(f5, off);
        }
        if (tid == 0) {
            accs[0] += f0; accs[1] += f1; accs[2] += f2;
            accs[3] += f3; accs[4] += f4; accs[5] += f5;
        }
    }
    if (fbin >= 0) {
        atomicSub(&lhist[fbin], 1u);
        krow[fa] = 0u;     // now positive: excluded from neg scans
    }
    __syncthreads();

    // ---- phase 2: k + threshold bin ----
    unsigned pos_t = (unsigned)accs[4];
    unsigned face_t = (unsigned)accs[5];
    unsigned num_pos = pos_t > 1u ? pos_t : 1u;
    unsigned neg_cnt = (unsigned)A - pos_t;
    unsigned k = 3u * num_pos; if (neg_cnt < k) k = neg_cnt;

    {
        unsigned c = (tid < NB2) ? lhist[tid] : 0u;
        sc[tid] = c; __syncthreads();
        #pragma unroll
        for (int off = 1; off < ST; off <<= 1) {
            unsigned add = (tid + off < ST) ? sc[tid + off] : 0u;
            __syncthreads();
            sc[tid] += add;
            __syncthreads();
        }
        if (tid < NB2) {
            unsigned excl = sc[tid] - c;
            if (excl < k && excl + c >= k) { s_t = tid; s_kk = k - excl; }
        }
        __syncthreads();
    }
    const int t = s_t;
    const unsigned kk_bin = s_kk;

    // ---- phase 3: fused sum(bins>t) + compact(bin==t) ----
    float nsum_top = 0.0f;
    for (int i = tid; i < A / 4; i += ST) {
        uint4 kv = krow4[i];
        #pragma unroll
        for (int j = 0; j < 4; ++j) {
            unsigned key = (&kv.x)[j];
            if (key != 0u) {
                float closs = __uint_as_float(key ^ 0x80000000u);
                int bin = vbin(closs);
                if (bin > t) {
                    nsum_top += closs;
                } else if (bin == t) {
                    unsigned off = atomicAdd(&s_candN, 1u);
                    if (off < CANDCAP) cand[off] = key;
                }
            }
        }
    }
    __syncthreads();
    const unsigned candN = s_candN;
    const bool fast = candN <= CANDCAP;

    // ---- phase 4: exact radix select within bin t ----
    unsigned pfx = 0, kk = kk_bin;
    for (int p = 0; p < 4; ++p) {
        if (tid < 256) lhist[tid] = 0;
        __syncthreads();
        const int shift = 24 - 8 * p;
        if (fast) {
            for (unsigned i = tid; i < candN; i += ST) {
                unsigned key = cand[i];
                if (p == 0 || (key >> (shift + 8)) == pfx)
                    atomicAdd(&lhist[(key >> shift) & 0xFFu], 1u);
            }
        } else {   // overflow fallback: full row with bin filter
            for (int a = tid; a < A; a += ST) {
                unsigned key = krow[a];
                if (key != 0u && vbin(__uint_as_float(key ^ 0x80000000u)) == t &&
                    (p == 0 || (key >> (shift + 8)) == pfx))
                    atomicAdd(&lhist[(key >> shift) & 0xFFu], 1u);
            }
        }
        __syncthreads();
        unsigned c = (tid < 256) ? lhist[tid] : 0u;
        sc[tid] = c; __syncthreads();
        #pragma unroll
        for (int off = 1; off < ST; off <<= 1) {
            unsigned add = (tid + off < ST) ? sc[tid + off] : 0u;
            __syncthreads();
            sc[tid] += add;
            __syncthreads();
        }
        if (tid < 256) {
            unsigned excl = sc[tid] - c;
            if (excl < kk && excl + c >= kk) {
                s_pfx = (pfx << 8) | (unsigned)tid;
                s_k2 = kk - excl;
            }
        }
        __syncthreads();
        pfx = s_pfx; kk = s_k2;
        __syncthreads();
    }
    const unsigned Tkey = pfx;
    const unsigned krem = kk;
    const float Tval = __uint_as_float(Tkey ^ 0x80000000u);

    // ---- phase 5: candidate sum + final reduce ----
    float csum = 0.0f;
    if (fast) {
        for (unsigned i = tid; i < candN; i += ST) {
            unsigned key = cand[i];
            if (key > Tkey) csum += __uint_as_float(key ^ 0x80000000u);
        }
    } else {
        for (int a = tid; a < A; a += ST) {
            unsigned key = krow[a];
            if (key != 0u) {
                float closs = __uint_as_float(key ^ 0x80000000u);
                if (vbin(closs) == t && key > Tkey) csum += closs;
            }
        }
    }
    red[tid] = nsum_top + csum; __syncthreads();
    for (int st = ST / 2; st > 0; st >>= 1) {
        if (tid < st) red[tid] += red[tid + st];
        __syncthreads();
    }
    if (tid == 0) {
        float* pr = partials + b * PF;
        pr[0] = accs[0]; pr[1] = accs[1]; pr[2] = accs[2]; pr[3] = accs[3];
        pr[4] = red[0] + (float)krem * Tval;
        pr[5] = (float)num_pos;
        pr[6] = (float)(face_t > 1u ? face_t : 1u);
    }
}

// ---------------------------------------------------------------------------
// K3: combine per-batch partials -> 5 scalar outputs.
// ---------------------------------------------------------------------------
__global__ void finalize_kernel(const float* __restrict__ partials,
                                float* __restrict__ out)
{
    int t = threadIdx.x;  // 64 threads = 1 wave
    float ps = partials[t * PF + 0], bs = partials[t * PF + 1];
    float ls = partials[t * PF + 2], gs = partials[t * PF + 3];
    float ns = partials[t * PF + 4], npos = partials[t * PF + 5];
    float nf = partials[t * PF + 6];
    for (int o = 32; o > 0; o >>= 1) {
        ps += __shfl_down(ps, o); bs += __shfl_down(bs, o);
        ls += __shfl_down(ls, o); gs += __shfl_down(gs, o);
        ns += __shfl_down(ns, o); npos += __shfl_down(npos, o);
        nf += __shfl_down(nf, o);
    }
    if (t == 0) {
        float tc = (ps + ns) / npos;
        float tb = bs / npos;
        float tl = ls / nf;
        float tg = gs / nf;
        out[0] = tc + 1.0f * tb + 0.5f * tl + 1.0f * tg;
        out[1] = tc; out[2] = tb; out[3] = tl; out[4] = tg;
    }
}

extern "C" void kernel_launch(void* const* d_in, const int* in_sizes, int n_in,
                              void* d_out, int out_size, void* d_ws, size_t ws_size,
                              hipStream_t stream) {
    const float* cls_logits = (const float*)d_in[0];
    const float* box_preds  = (const float*)d_in[1];
    const float* lmk_preds  = (const float*)d_in[2];
    const float* gaze_preds = (const float*)d_in[3];
    const float* anchors    = (const float*)d_in[4];
    const float* gt_boxes   = (const float*)d_in[5];
    const int*   gt_labels  = (const int*)d_in[6];
    const float* gt_lmk     = (const float*)d_in[7];
    const float* gt_gaze    = (const float*)d_in[8];

    char* ws = (char*)d_ws;
    signed char* matches = (signed char*)ws;             ws += (size_t)B * A;               // 1.6 MB
    unsigned long long* gbest = (unsigned long long*)ws; ws += (size_t)B * G * 8;           // 16 KB
    unsigned* negkey = (unsigned*)ws;                    ws += (size_t)B * A * 4;           // 6.5 MB
    unsigned* bhist = (unsigned*)ws;                     ws += (size_t)B * MSPLIT * NB2 * 4; // 3.3 MB
    unsigned* candbuf = (unsigned*)ws;                   ws += (size_t)B * CANDCAP * 4;     // 2 MB
    float* psplit = (float*)ws;                          ws += (size_t)B * MSPLIT * PF * 4; // 102 KB
    float* partials = (float*)ws;
    float* out = (float*)d_out;

    hipLaunchKernelGGL(init_kernel, dim3((B * G + 255) / 256), dim3(256), 0, stream, gbest);
    hipLaunchKernelGGL(fused_kernel, dim3(B, MSPLIT), dim3(256), 0, stream,
                       cls_logits, box_preds, lmk_preds, gaze_preds, anchors,
                       gt_boxes, gt_labels, gt_lmk, gt_gaze, matches, gbest,
                       negkey, bhist, psplit);
    hipLaunchKernelGGL(select_kernel, dim3(B), dim3(ST), 0, stream,
                       cls_logits, box_preds, lmk_preds, gaze_preds, anchors,
                       gt_boxes, gt_labels, gt_lmk, gt_gaze, matches, gbest,
                       negkey, bhist, psplit, candbuf, partials);
    hipLaunchKernelGGL(finalize_kernel, dim3(1), dim3(64), 0, stream,
                       partials, out);
}

// Round 10
// 56.456 us; speedup vs baseline: 2.3130x; 1.1041x over previous
//
#include <hip/hip_runtime.h>
#include <stdint.h>

#define B 64
#define G 32
#define A 25600
#define NC 2
#define NL 5
#define IOU_T 0.5f
#define VAR_C 0.1f
#define VAR_S 0.2f

#define MSPLIT 50
#define MCH (A / MSPLIT)    // 512 anchors per fused block, 2 per thread
#define PF 8                // fields per psplit record

#define NB2 256             // coarse value-histogram bins
#define BSCALE2 20.0f       // bin = int(closs * 20), clamped to 255
#define CANDCAP 8192        // per-batch candidate buffer capacity
#define ST 512              // select_kernel threads

__device__ __forceinline__ float sl1(float x) {
    float ax = fabsf(x);
    return ax < 1.0f ? 0.5f * ax * ax : ax - 0.5f;
}

__device__ __forceinline__ int vbin(float closs) {
    int bin = (int)(closs * BSCALE2);
    return bin < 0 ? 0 : (bin > NB2 - 1 ? NB2 - 1 : bin);
}

// ---------------------------------------------------------------------------
// K1 FUSED match+loss: grid (B, MSPLIT) x 256, 2 anchors per thread.
//  - wave-bbox early-out: one uniform 4-compare per (wave,gt) skips the
//    per-lane IoU math when no lane can intersect (exact: all ious would be
//    +0; first-max argmax preserved by the best<0 fixup)
//  - per-(block,gt) best key -> gsplit by PLAIN OVERWRITE (no atomics, no
//    init kernel); select max-reduces the 50 records
//  - negatives: monotonic key -> negkey + 256-bin LDS hist -> bhist record
// ---------------------------------------------------------------------------
__global__ __launch_bounds__(256) void fused_kernel(
    const float* __restrict__ cls_logits, const float* __restrict__ box_preds,
    const float* __restrict__ lmk_preds, const float* __restrict__ gaze_preds,
    const float* __restrict__ anchors, const float* __restrict__ gt_boxes,
    const int* __restrict__ gt_labels, const float* __restrict__ gt_lmk,
    const float* __restrict__ gt_gaze, signed char* __restrict__ matches,
    unsigned long long* __restrict__ gsplit, unsigned* __restrict__ negkey,
    unsigned* __restrict__ bhist, float* __restrict__ psplit)
{
    const int b = blockIdx.x, s = blockIdx.y, tid = threadIdx.x;
    const int lane = tid & 63;
    __shared__ float4 sbox[G];
    __shared__ int sgorig[G];
    __shared__ unsigned long long sbest[G];
    __shared__ unsigned long long fin[G];
    __shared__ int s_nv;
    __shared__ float sgb[G * 4], slmk[G * NL * 2], sgz[G * 2];
    __shared__ int slab[G];
    __shared__ unsigned lhist[NB2];
    __shared__ float red[256];

    if (tid < G) {
        sbest[tid] = 0ULL;
        int valid = gt_labels[b * G + tid] > 0;
        unsigned long long mask = __ballot(valid);
        int pfx = __popcll(mask & ((1ULL << tid) - 1ULL));
        if (valid) {
            sbox[pfx] = *(const float4*)(gt_boxes + (b * G + tid) * 4);
            sgorig[pfx] = tid;
        }
        if (tid == 0) s_nv = (int)__popcll(mask);
    }
    for (int i = tid; i < G * 4; i += 256) sgb[i] = gt_boxes[b * G * 4 + i];
    for (int i = tid; i < G * NL * 2; i += 256) slmk[i] = gt_lmk[b * G * NL * 2 + i];
    for (int i = tid; i < G * 2; i += 256) sgz[i] = gt_gaze[b * G * 2 + i];
    if (tid < G) slab[tid] = gt_labels[b * G + tid];
    lhist[tid] = 0;
    __syncthreads();
    const int nv = s_nv;

    signed char* mrow = matches + (size_t)b * A;
    const int a0 = s * MCH;
    const int aL = a0 + tid, aH = aL + 256;

    // ---- match phase ----
    float4 anL = *(const float4*)(anchors + aL * 4);
    float4 anH = *(const float4*)(anchors + aH * 4);
    float axL0 = anL.x - anL.z * 0.5f, ayL0 = anL.y - anL.w * 0.5f;
    float axL1 = anL.x + anL.z * 0.5f, ayL1 = anL.y + anL.w * 0.5f;
    float aaL = (axL1 - axL0) * (ayL1 - ayL0);   // mirror reference float path
    float axH0 = anH.x - anH.z * 0.5f, ayH0 = anH.y - anH.w * 0.5f;
    float axH1 = anH.x + anH.z * 0.5f, ayH1 = anH.y + anH.w * 0.5f;
    float aaH = (axH1 - axH0) * (ayH1 - ayH0);

    // wave bbox of the 128 anchors this wave owns
    float wx0 = fminf(axL0, axH0), wy0 = fminf(ayL0, ayH0);
    float wx1 = fmaxf(axL1, axH1), wy1 = fmaxf(ayL1, ayH1);
    #pragma unroll
    for (int off = 32; off > 0; off >>= 1) {
        wx0 = fminf(wx0, __shfl_down(wx0, off));
        wy0 = fminf(wy0, __shfl_down(wy0, off));
        wx1 = fmaxf(wx1, __shfl_down(wx1, off));
        wy1 = fmaxf(wy1, __shfl_down(wy1, off));
    }
    wx0 = __shfl(wx0, 0); wy0 = __shfl(wy0, 0);
    wx1 = __shfl(wx1, 0); wy1 = __shfl(wy1, 0);

    float bestL = -2.0f, bestH = -2.0f;
    int bciL = 0, bciH = 0;
    for (int ci = 0; ci < nv; ++ci) {
        float4 bb = sbox[ci];                       // broadcast ds_read_b128
        if (bb.x < wx1 && bb.z > wx0 && bb.y < wy1 && bb.w > wy0) {
            float area = (bb.z - bb.x) * (bb.w - bb.y); // reference formula
            float iwL = fmaxf(fminf(bb.z, axL1) - fmaxf(bb.x, axL0), 0.0f);
            float ihL = fmaxf(fminf(bb.w, ayL1) - fmaxf(bb.y, ayL0), 0.0f);
            float interL = iwL * ihL;
            float iwH = fmaxf(fminf(bb.z, axH1) - fmaxf(bb.x, axH0), 0.0f);
            float ihH = fmaxf(fminf(bb.w, ayH1) - fmaxf(bb.y, ayH0), 0.0f);
            float interH = iwH * ihH;
            float iouL = 0.0f, iouH = 0.0f;             // exact: 0/den == +0.0
            if (__any(interL > 0.0f || interH > 0.0f)) { // wave-uniform skip
                iouL = interL / (area + aaL - interL + 1e-9f);
                iouH = interH / (area + aaH - interH + 1e-9f);
                unsigned long long keyL =
                    ((unsigned long long)__float_as_uint(iouL) << 32) |
                    (unsigned)(0xFFFFFFFFu - (unsigned)aL);
                unsigned long long keyH =
                    ((unsigned long long)__float_as_uint(iouH) << 32) |
                    (unsigned)(0xFFFFFFFFu - (unsigned)aH);
                unsigned long long km = keyL > keyH ? keyL : keyH;
                #pragma unroll
                for (int off = 32; off > 0; off >>= 1) {
                    unsigned long long o = __shfl_down(km, off);
                    if (o > km) km = o;
                }
                if (lane == 0 && km > sbest[ci]) atomicMax(&sbest[ci], km);
            }
            if (iouL > bestL) { bestL = iouL; bciL = ci; }  // first-max wins
            if (iouH > bestH) { bestH = iouH; bciH = ci; }
        } else {
            // all lanes: iou == +0 exactly; first-max argmax fixup
            if (bestL < 0.0f) { bestL = 0.0f; bciL = ci; }
            if (bestH < 0.0f) { bestH = 0.0f; bciH = ci; }
        }
    }
    const int vL = (bestL >= IOU_T) ? sgorig[bciL] : -1;
    const int vH = (bestH >= IOU_T) ? sgorig[bciH] : -1;
    mrow[aL] = (signed char)vL;
    mrow[aH] = (signed char)vH;

    // ---- loss phase (consumes vL/vH from registers) ----
    const float* lrow = cls_logits + (size_t)b * A * NC;
    unsigned* krow = negkey + (size_t)b * A;

    float pos_sum = 0, box_sum = 0, lmk_sum = 0, gaze_sum = 0;
    float pos_cnt = 0, face_cnt = 0;

    #pragma unroll
    for (int h = 0; h < 2; ++h) {
        const int a = h ? aH : aL;
        const int v = h ? vH : vL;
        const float4 an = h ? anH : anL;
        float2 xl = *(const float2*)(lrow + a * 2);
        float x0 = xl.x, x1 = xl.y;
        float mx = fmaxf(x0, x1);
        float lse = mx + logf(expf(x0 - mx) + expf(x1 - mx));
        unsigned key = 0;
        if (v < 0) {
            float closs = lse - x0;   // label 0; closs > 0
            unsigned bits = __float_as_uint(closs);
            key = bits ^ ((bits & 0x80000000u) ? 0xFFFFFFFFu : 0x80000000u);
            atomicAdd(&lhist[vbin(closs)], 1u);
        } else {
            int m = v;
            int lab = slab[m];
            float xc = (lab >= 1) ? x1 : x0;   // NC==2
            pos_sum += lse - xc;
            pos_cnt += 1.0f;
            float dcx = an.x, dcy = an.y, dw = an.z, dh = an.w;
            float bx0 = sgb[m * 4], by0 = sgb[m * 4 + 1];
            float bx1 = sgb[m * 4 + 2], by1 = sgb[m * 4 + 3];
            float gcx = (bx0 + bx1) * 0.5f, gcy = (by0 + by1) * 0.5f;
            float gw = bx1 - bx0, gh = by1 - by0;
            float off0 = ((gcx - dcx) / dw) / VAR_C;
            float off1 = ((gcy - dcy) / dh) / VAR_C;
            float off2 = logf(fmaxf(gw / dw, 1e-6f)) / VAR_S;
            float off3 = logf(fmaxf(gh / dh, 1e-6f)) / VAR_S;
            float4 bp = *(const float4*)(box_preds + ((size_t)b * A + a) * 4);
            box_sum += sl1(bp.x - off0) + sl1(bp.y - off1) +
                       sl1(bp.z - off2) + sl1(bp.w - off3);
            if (lab == 1) {  // FACE
                face_cnt += 1.0f;
                const float* lp = lmk_preds + ((size_t)b * A + a) * (NL * 2);
                #pragma unroll
                for (int i = 0; i < NL; ++i) {
                    float tx = ((slmk[m * NL * 2 + 2 * i] - dcx) / dw) / VAR_C;
                    float ty = ((slmk[m * NL * 2 + 2 * i + 1] - dcy) / dh) / VAR_C;
                    lmk_sum += sl1(lp[2 * i] - tx) + sl1(lp[2 * i + 1] - ty);
                }
                const float* gp = gaze_preds + ((size_t)b * A + a) * 2;
                gaze_sum += sl1(gp[0] - sgz[m * 2]) + sl1(gp[1] - sgz[m * 2 + 1]);
            }
        }
        krow[a] = key;
    }

    auto redf = [&](float v) -> float {
        red[tid] = v; __syncthreads();
        for (int st = 128; st > 0; st >>= 1) {
            if (tid < st) red[tid] += red[tid + st];
            __syncthreads();
        }
        float r = red[0]; __syncthreads();
        return r;
    };
    float f0 = redf(pos_sum), f1 = redf(box_sum), f2 = redf(lmk_sum);
    float f3 = redf(gaze_sum), f4 = redf(pos_cnt), f5 = redf(face_cnt);
    if (tid == 0) {
        float* pr = psplit + (b * MSPLIT + s) * PF;
        pr[0] = f0; pr[1] = f1; pr[2] = f2; pr[3] = f3; pr[4] = f4; pr[5] = f5;
    }
    bhist[(b * MSPLIT + s) * NB2 + tid] = lhist[tid];   // coalesced store

    // per-(block,gt) best keys -> gsplit by plain overwrite (orig-g indexed)
    if (tid < G) fin[tid] = 0ULL;
    __syncthreads();
    if (tid < nv) fin[sgorig[tid]] = sbest[tid];
    __syncthreads();
    if (tid < G) gsplit[((size_t)b * MSPLIT + s) * G + tid] = fin[tid];
}

// ---------------------------------------------------------------------------
// K2 select (+forced-match fixup, +per-batch reduce): grid B x 512.
// Phase 0: merge 50 hists + psplit records.
// Phase 1: FIXUP — lanes 0..31 max-reduce gsplit over 50 splits, dedup
//   last-wins via shfl, subtract forced anchors' neg contributions (hist
//   bin, negkey=0) and add their pos contributions. Block-local.
// Phase 2+: threshold bin (parallel suffix scan), fused sum+compact scan,
//   exact radix over candidates, deterministic sums -> partials[b].
// ---------------------------------------------------------------------------
__global__ __launch_bounds__(ST) void select_kernel(
    const float* __restrict__ cls_logits, const float* __restrict__ box_preds,
    const float* __restrict__ lmk_preds, const float* __restrict__ gaze_preds,
    const float* __restrict__ anchors, const float* __restrict__ gt_boxes,
    const int* __restrict__ gt_labels, const float* __restrict__ gt_lmk,
    const float* __restrict__ gt_gaze, const signed char* __restrict__ matches,
    const unsigned long long* __restrict__ gsplit,
    unsigned* __restrict__ negkey, const unsigned* __restrict__ bhist,
    const float* __restrict__ psplit, unsigned* __restrict__ candbuf,
    float* __restrict__ partials)
{
    const int b = blockIdx.x, tid = threadIdx.x;
    __shared__ unsigned lhist[NB2];
    __shared__ unsigned sc[ST];
    __shared__ float red[ST];
    __shared__ float accs[8];
    __shared__ int s_t;
    __shared__ unsigned s_kk, s_candN, s_pfx, s_k2;

    unsigned* krow = negkey + (size_t)b * A;
    const uint4* krow4 = (const uint4*)krow;
    const float* lrow = cls_logits + (size_t)b * A * NC;
    unsigned* cand = candbuf + (size_t)b * CANDCAP;

    // ---- phase 0 ----
    if (tid < 6) {
        float v = 0;
        for (int s2 = 0; s2 < MSPLIT; ++s2) v += psplit[(b * MSPLIT + s2) * PF + tid];
        accs[tid] = v;
    }
    if (tid < NB2) {
        unsigned v = 0;
        const unsigned* hb = bhist + (size_t)b * MSPLIT * NB2 + tid;
        for (int s2 = 0; s2 < MSPLIT; ++s2) v += hb[s2 * NB2];
        lhist[tid] = v;
    }
    if (tid == 0) s_candN = 0;
    __syncthreads();

    // ---- phase 1: fixup (forced matches) ----
    float f0 = 0, f1 = 0, f2 = 0, f3 = 0, f4 = 0, f5 = 0;
    int fbin = -1, fa = -1;
    if (tid < 32) {
        const int g = tid;
        int lab = gt_labels[b * G + g];
        unsigned long long kb = 0ULL;
        const unsigned long long* gs = gsplit + (size_t)b * MSPLIT * G + g;
        for (int s2 = 0; s2 < MSPLIT; ++s2) {
            unsigned long long v = gs[(size_t)s2 * G];
            if (v > kb) kb = v;
        }
        int a_c = -1;
        if (lab > 0 && kb != 0ULL) {
            unsigned a = 0xFFFFFFFFu - (unsigned)(kb & 0xFFFFFFFFu);
            if (matches[(size_t)b * A + a] < 0) a_c = (int)a;   // threshold wins
        }
        bool win = a_c >= 0;
        for (int j = 0; j < 32; ++j) {                 // last-wins dedup
            int aj = __shfl(a_c, j);
            if (j > g && a_c >= 0 && aj == a_c) win = false;
        }
        if (win) {
            const int a = a_c;
            float2 xl = *(const float2*)(lrow + a * 2);
            float x0 = xl.x, x1 = xl.y;
            float mx = fmaxf(x0, x1);
            float lse = mx + logf(expf(x0 - mx) + expf(x1 - mx));
            float xc = (lab >= 1) ? x1 : x0;
            f0 = lse - xc; f4 = 1.0f;
            float4 an = *(const float4*)(anchors + a * 4);
            const float* gb = gt_boxes + (b * G + g) * 4;
            float bx0 = gb[0], by0 = gb[1], bx1 = gb[2], by1 = gb[3];
            float gcx = (bx0 + bx1) * 0.5f, gcy = (by0 + by1) * 0.5f;
            float gw = bx1 - bx0, gh = by1 - by0;
            float off0 = ((gcx - an.x) / an.z) / VAR_C;
            float off1 = ((gcy - an.y) / an.w) / VAR_C;
            float off2 = logf(fmaxf(gw / an.z, 1e-6f)) / VAR_S;
            float off3 = logf(fmaxf(gh / an.w, 1e-6f)) / VAR_S;
            float4 bp = *(const float4*)(box_preds + ((size_t)b * A + a) * 4);
            f1 = sl1(bp.x - off0) + sl1(bp.y - off1) +
                 sl1(bp.z - off2) + sl1(bp.w - off3);
            if (lab == 1) {
                f5 = 1.0f;
                const float* gl = gt_lmk + (b * G + g) * NL * 2;
                const float* lp = lmk_preds + ((size_t)b * A + a) * (NL * 2);
                #pragma unroll
                for (int i = 0; i < NL; ++i) {
                    float tx = ((gl[2 * i] - an.x) / an.z) / VAR_C;
                    float ty = ((gl[2 * i + 1] - an.y) / an.w) / VAR_C;
                    f2 += sl1(lp[2 * i] - tx) + sl1(lp[2 * i + 1] - ty);
                }
                const float* gz = gt_gaze + (b * G + g) * 2;
                const float* gp = gaze_preds + ((size_t)b * A + a) * 2;
                f3 = sl1(gp[0] - gz[0]) + sl1(gp[1] - gz[1]);
            }
            unsigned key = krow[a];
            float closs = __uint_as_float(key ^ 0x80000000u);
            fbin = vbin(closs); fa = a;
        }
    }
    if (tid < 64) {   // whole wave 0 reduces (lanes 32..63 carry zeros)
        #pragma unroll
        for (int off = 16; off > 0; off >>= 1) {
            f0 += __shfl_down(f0, off); f1 += __shfl_down(f1, off);
            f2 += __shfl_down(f2, off); f3 += __shfl_down(f3, off);
            f4 += __shfl_down(f4, off); f5 += __shfl_down(f5, off);
        }
        if (tid == 0) {
            accs[0] += f0; accs[1] += f1; accs[2] += f2;
            accs[3] += f3; accs[4] += f4; accs[5] += f5;
        }
    }
    if (fbin >= 0) {
        atomicSub(&lhist[fbin], 1u);
        krow[fa] = 0u;     // now positive: excluded from neg scans
    }
    __syncthreads();

    // ---- phase 2: k + threshold bin ----
    unsigned pos_t = (unsigned)accs[4];
    unsigned face_t = (unsigned)accs[5];
    unsigned num_pos = pos_t > 1u ? pos_t : 1u;
    unsigned neg_cnt = (unsigned)A - pos_t;
    unsigned k = 3u * num_pos; if (neg_cnt < k) k = neg_cnt;

    {
        unsigned c = (tid < NB2) ? lhist[tid] : 0u;
        sc[tid] = c; __syncthreads();
        #pragma unroll
        for (int off = 1; off < ST; off <<= 1) {
            unsigned add = (tid + off < ST) ? sc[tid + off] : 0u;
            __syncthreads();
            sc[tid] += add;
            __syncthreads();
        }
        if (tid < NB2) {
            unsigned excl = sc[tid] - c;
            if (excl < k && excl + c >= k) { s_t = tid; s_kk = k - excl; }
        }
        __syncthreads();
    }
    const int t = s_t;
    const unsigned kk_bin = s_kk;

    // ---- phase 3: fused sum(bins>t) + compact(bin==t) ----
    float nsum_top = 0.0f;
    for (int i = tid; i < A / 4; i += ST) {
        uint4 kv = krow4[i];
        #pragma unroll
        for (int j = 0; j < 4; ++j) {
            unsigned key = (&kv.x)[j];
            if (key != 0u) {
                float closs = __uint_as_float(key ^ 0x80000000u);
                int bin = vbin(closs);
                if (bin > t) {
                    nsum_top += closs;
                } else if (bin == t) {
                    unsigned off = atomicAdd(&s_candN, 1u);
                    if (off < CANDCAP) cand[off] = key;
                }
            }
        }
    }
    __syncthreads();
    const unsigned candN = s_candN;
    const bool fast = candN <= CANDCAP;

    // ---- phase 4: exact radix select within bin t ----
    unsigned pfx = 0, kk = kk_bin;
    for (int p = 0; p < 4; ++p) {
        if (tid < 256) lhist[tid] = 0;
        __syncthreads();
        const int shift = 24 - 8 * p;
        if (fast) {
            for (unsigned i = tid; i < candN; i += ST) {
                unsigned key = cand[i];
                if (p == 0 || (key >> (shift + 8)) == pfx)
                    atomicAdd(&lhist[(key >> shift) & 0xFFu], 1u);
            }
        } else {   // overflow fallback: full row with bin filter
            for (int a = tid; a < A; a += ST) {
                unsigned key = krow[a];
                if (key != 0u && vbin(__uint_as_float(key ^ 0x80000000u)) == t &&
                    (p == 0 || (key >> (shift + 8)) == pfx))
                    atomicAdd(&lhist[(key >> shift) & 0xFFu], 1u);
            }
        }
        __syncthreads();
        unsigned c = (tid < 256) ? lhist[tid] : 0u;
        sc[tid] = c; __syncthreads();
        #pragma unroll
        for (int off = 1; off < ST; off <<= 1) {
            unsigned add = (tid + off < ST) ? sc[tid + off] : 0u;
            __syncthreads();
            sc[tid] += add;
            __syncthreads();
        }
        if (tid < 256) {
            unsigned excl = sc[tid] - c;
            if (excl < kk && excl + c >= kk) {
                s_pfx = (pfx << 8) | (unsigned)tid;
                s_k2 = kk - excl;
            }
        }
        __syncthreads();
        pfx = s_pfx; kk = s_k2;
        __syncthreads();
    }
    const unsigned Tkey = pfx;
    const unsigned krem = kk;
    const float Tval = __uint_as_float(Tkey ^ 0x80000000u);

    // ---- phase 5: candidate sum + final reduce ----
    float csum = 0.0f;
    if (fast) {
        for (unsigned i = tid; i < candN; i += ST) {
            unsigned key = cand[i];
            if (key > Tkey) csum += __uint_as_float(key ^ 0x80000000u);
        }
    } else {
        for (int a = tid; a < A; a += ST) {
            unsigned key = krow[a];
            if (key != 0u) {
                float closs = __uint_as_float(key ^ 0x80000000u);
                if (vbin(closs) == t && key > Tkey) csum += closs;
            }
        }
    }
    red[tid] = nsum_top + csum; __syncthreads();
    for (int st = ST / 2; st > 0; st >>= 1) {
        if (tid < st) red[tid] += red[tid + st];
        __syncthreads();
    }
    if (tid == 0) {
        float* pr = partials + b * PF;
        pr[0] = accs[0]; pr[1] = accs[1]; pr[2] = accs[2]; pr[3] = accs[3];
        pr[4] = red[0] + (float)krem * Tval;
        pr[5] = (float)num_pos;
        pr[6] = (float)(face_t > 1u ? face_t : 1u);
    }
}

// ---------------------------------------------------------------------------
// K3: combine per-batch partials -> 5 scalar outputs.
// ---------------------------------------------------------------------------
__global__ void finalize_kernel(const float* __restrict__ partials,
                                float* __restrict__ out)
{
    int t = threadIdx.x;  // 64 threads = 1 wave
    float ps = partials[t * PF + 0], bs = partials[t * PF + 1];
    float ls = partials[t * PF + 2], gs = partials[t * PF + 3];
    float ns = partials[t * PF + 4], npos = partials[t * PF + 5];
    float nf = partials[t * PF + 6];
    for (int o = 32; o > 0; o >>= 1) {
        ps += __shfl_down(ps, o); bs += __shfl_down(bs, o);
        ls += __shfl_down(ls, o); gs += __shfl_down(gs, o);
        ns += __shfl_down(ns, o); npos += __shfl_down(npos, o);
        nf += __shfl_down(nf, o);
    }
    if (t == 0) {
        float tc = (ps + ns) / npos;
        float tb = bs / npos;
        float tl = ls / nf;
        float tg = gs / nf;
        out[0] = tc + 1.0f * tb + 0.5f * tl + 1.0f * tg;
        out[1] = tc; out[2] = tb; out[3] = tl; out[4] = tg;
    }
}

extern "C" void kernel_launch(void* const* d_in, const int* in_sizes, int n_in,
                              void* d_out, int out_size, void* d_ws, size_t ws_size,
                              hipStream_t stream) {
    const float* cls_logits = (const float*)d_in[0];
    const float* box_preds  = (const float*)d_in[1];
    const float* lmk_preds  = (const float*)d_in[2];
    const float* gaze_preds = (const float*)d_in[3];
    const float* anchors    = (const float*)d_in[4];
    const float* gt_boxes   = (const float*)d_in[5];
    const int*   gt_labels  = (const int*)d_in[6];
    const float* gt_lmk     = (const float*)d_in[7];
    const float* gt_gaze    = (const float*)d_in[8];

    char* ws = (char*)d_ws;
    signed char* matches = (signed char*)ws;             ws += (size_t)B * A;                // 1.6 MB
    unsigned long long* gsplit = (unsigned long long*)ws; ws += (size_t)B * MSPLIT * G * 8;  // 0.82 MB
    unsigned* negkey = (unsigned*)ws;                    ws += (size_t)B * A * 4;            // 6.5 MB
    unsigned* bhist = (unsigned*)ws;                     ws += (size_t)B * MSPLIT * NB2 * 4; // 3.3 MB
    unsigned* candbuf = (unsigned*)ws;                   ws += (size_t)B * CANDCAP * 4;      // 2 MB
    float* psplit = (float*)ws;                          ws += (size_t)B * MSPLIT * PF * 4;  // 102 KB
    float* partials = (float*)ws;
    float* out = (float*)d_out;

    hipLaunchKernelGGL(fused_kernel, dim3(B, MSPLIT), dim3(256), 0, stream,
                       cls_logits, box_preds, lmk_preds, gaze_preds, anchors,
                       gt_boxes, gt_labels, gt_lmk, gt_gaze, matches, gsplit,
                       negkey, bhist, psplit);
    hipLaunchKernelGGL(select_kernel, dim3(B), dim3(ST), 0, stream,
                       cls_logits, box_preds, lmk_preds, gaze_preds, anchors,
                       gt_boxes, gt_labels, gt_lmk, gt_gaze, matches, gsplit,
                       negkey, bhist, psplit, candbuf, partials);
    hipLaunchKernelGGL(finalize_kernel, dim3(1), dim3(64), 0, stream,
                       partials, out);
}

// Round 11
// 52.892 us; speedup vs baseline: 2.4688x; 1.0674x over previous
//
#include <hip/hip_runtime.h>
#include <stdint.h>

#define B 64
#define G 32
#define A 25600
#define NC 2
#define NL 5
#define IOU_T 0.5f
#define VAR_C 0.1f
#define VAR_S 0.2f

#define MSPLIT 50
#define MCH (A / MSPLIT)    // 512 anchors per fused block, 2 per thread
#define PF 8                // fields per psplit record

#define NB2 256             // coarse value-histogram bins
#define BSCALE2 20.0f       // bin = int(closs * 20), clamped to 255
#define CANDCAP 8192        // per-batch candidate buffer capacity
#define ST 512              // select_kernel threads
#define NW (ST / 64)        // select waves

__device__ __forceinline__ float sl1(float x) {
    float ax = fabsf(x);
    return ax < 1.0f ? 0.5f * ax * ax : ax - 0.5f;
}

__device__ __forceinline__ int vbin(float closs) {
    int bin = (int)(closs * BSCALE2);
    return bin < 0 ? 0 : (bin > NB2 - 1 ? NB2 - 1 : bin);
}

// ---------------------------------------------------------------------------
// K1 FUSED match+loss: grid (B, MSPLIT) x 256, 2 anchors per thread.
//  - wave-bbox early-out for the IoU loop (exact; first-max argmax fixup)
//  - epilogue: wave shfl reduces + 1 LDS hop (2 barriers, not 96)
//  - per-wave 256-bin neg hist (4x less LDS atomic contention)
//  - per-(block,gt) best keys -> gsplit plain overwrite via sinv map
//  - resets gdone for select's last-block finalize
// ---------------------------------------------------------------------------
__global__ __launch_bounds__(256) void fused_kernel(
    const float* __restrict__ cls_logits, const float* __restrict__ box_preds,
    const float* __restrict__ lmk_preds, const float* __restrict__ gaze_preds,
    const float* __restrict__ anchors, const float* __restrict__ gt_boxes,
    const int* __restrict__ gt_labels, const float* __restrict__ gt_lmk,
    const float* __restrict__ gt_gaze, signed char* __restrict__ matches,
    unsigned long long* __restrict__ gsplit, unsigned* __restrict__ negkey,
    unsigned* __restrict__ bhist, float* __restrict__ psplit,
    unsigned* __restrict__ gdone)
{
    const int b = blockIdx.x, s = blockIdx.y, tid = threadIdx.x;
    const int lane = tid & 63, wave = tid >> 6;
    __shared__ float4 sbox[G];
    __shared__ int sgorig[G], sinv[G];
    __shared__ unsigned long long sbest[G];
    __shared__ int s_nv;
    __shared__ float sgb[G * 4], slmk[G * NL * 2], sgz[G * 2];
    __shared__ int slab[G];
    __shared__ unsigned lhist[4][NB2];
    __shared__ float wred[4][8];

    if (b == 0 && s == 0 && tid == 0) *gdone = 0u;   // reset for select

    if (tid < G) {
        sbest[tid] = 0ULL;
        int valid = gt_labels[b * G + tid] > 0;
        unsigned long long mask = __ballot(valid);
        int pfx = __popcll(mask & ((1ULL << tid) - 1ULL));
        sinv[tid] = valid ? pfx : -1;
        if (valid) {
            sbox[pfx] = *(const float4*)(gt_boxes + (b * G + tid) * 4);
            sgorig[pfx] = tid;
        }
        if (tid == 0) s_nv = (int)__popcll(mask);
    }
    for (int i = tid; i < G * 4; i += 256) sgb[i] = gt_boxes[b * G * 4 + i];
    for (int i = tid; i < G * NL * 2; i += 256) slmk[i] = gt_lmk[b * G * NL * 2 + i];
    for (int i = tid; i < G * 2; i += 256) sgz[i] = gt_gaze[b * G * 2 + i];
    if (tid < G) slab[tid] = gt_labels[b * G + tid];
    for (int i = tid; i < 4 * NB2; i += 256) ((unsigned*)lhist)[i] = 0u;
    __syncthreads();
    const int nv = s_nv;

    signed char* mrow = matches + (size_t)b * A;
    const int a0 = s * MCH;
    const int aL = a0 + tid, aH = aL + 256;

    // ---- match phase ----
    float4 anL = *(const float4*)(anchors + aL * 4);
    float4 anH = *(const float4*)(anchors + aH * 4);
    float axL0 = anL.x - anL.z * 0.5f, ayL0 = anL.y - anL.w * 0.5f;
    float axL1 = anL.x + anL.z * 0.5f, ayL1 = anL.y + anL.w * 0.5f;
    float aaL = (axL1 - axL0) * (ayL1 - ayL0);   // mirror reference float path
    float axH0 = anH.x - anH.z * 0.5f, ayH0 = anH.y - anH.w * 0.5f;
    float axH1 = anH.x + anH.z * 0.5f, ayH1 = anH.y + anH.w * 0.5f;
    float aaH = (axH1 - axH0) * (ayH1 - ayH0);

    // wave bbox of the 128 anchors this wave owns
    float wx0 = fminf(axL0, axH0), wy0 = fminf(ayL0, ayH0);
    float wx1 = fmaxf(axL1, axH1), wy1 = fmaxf(ayL1, ayH1);
    #pragma unroll
    for (int off = 32; off > 0; off >>= 1) {
        wx0 = fminf(wx0, __shfl_down(wx0, off));
        wy0 = fminf(wy0, __shfl_down(wy0, off));
        wx1 = fmaxf(wx1, __shfl_down(wx1, off));
        wy1 = fmaxf(wy1, __shfl_down(wy1, off));
    }
    wx0 = __shfl(wx0, 0); wy0 = __shfl(wy0, 0);
    wx1 = __shfl(wx1, 0); wy1 = __shfl(wy1, 0);

    float bestL = -2.0f, bestH = -2.0f;
    int bciL = 0, bciH = 0;
    for (int ci = 0; ci < nv; ++ci) {
        float4 bb = sbox[ci];                       // broadcast ds_read_b128
        if (bb.x < wx1 && bb.z > wx0 && bb.y < wy1 && bb.w > wy0) {
            float area = (bb.z - bb.x) * (bb.w - bb.y); // reference formula
            float iwL = fmaxf(fminf(bb.z, axL1) - fmaxf(bb.x, axL0), 0.0f);
            float ihL = fmaxf(fminf(bb.w, ayL1) - fmaxf(bb.y, ayL0), 0.0f);
            float interL = iwL * ihL;
            float iwH = fmaxf(fminf(bb.z, axH1) - fmaxf(bb.x, axH0), 0.0f);
            float ihH = fmaxf(fminf(bb.w, ayH1) - fmaxf(bb.y, ayH0), 0.0f);
            float interH = iwH * ihH;
            float iouL = 0.0f, iouH = 0.0f;             // exact: 0/den == +0.0
            if (__any(interL > 0.0f || interH > 0.0f)) { // wave-uniform skip
                iouL = interL / (area + aaL - interL + 1e-9f);
                iouH = interH / (area + aaH - interH + 1e-9f);
                unsigned long long keyL =
                    ((unsigned long long)__float_as_uint(iouL) << 32) |
                    (unsigned)(0xFFFFFFFFu - (unsigned)aL);
                unsigned long long keyH =
                    ((unsigned long long)__float_as_uint(iouH) << 32) |
                    (unsigned)(0xFFFFFFFFu - (unsigned)aH);
                unsigned long long km = keyL > keyH ? keyL : keyH;
                #pragma unroll
                for (int off = 32; off > 0; off >>= 1) {
                    unsigned long long o = __shfl_down(km, off);
                    if (o > km) km = o;
                }
                if (lane == 0 && km > sbest[ci]) atomicMax(&sbest[ci], km);
            }
            if (iouL > bestL) { bestL = iouL; bciL = ci; }  // first-max wins
            if (iouH > bestH) { bestH = iouH; bciH = ci; }
        } else {
            // all lanes: iou == +0 exactly; first-max argmax fixup
            if (bestL < 0.0f) { bestL = 0.0f; bciL = ci; }
            if (bestH < 0.0f) { bestH = 0.0f; bciH = ci; }
        }
    }
    const int vL = (bestL >= IOU_T) ? sgorig[bciL] : -1;
    const int vH = (bestH >= IOU_T) ? sgorig[bciH] : -1;
    mrow[aL] = (signed char)vL;
    mrow[aH] = (signed char)vH;

    // ---- loss phase (consumes vL/vH from registers) ----
    const float* lrow = cls_logits + (size_t)b * A * NC;
    unsigned* krow = negkey + (size_t)b * A;

    float pos_sum = 0, box_sum = 0, lmk_sum = 0, gaze_sum = 0;
    float pos_cnt = 0, face_cnt = 0;

    #pragma unroll
    for (int h = 0; h < 2; ++h) {
        const int a = h ? aH : aL;
        const int v = h ? vH : vL;
        const float4 an = h ? anH : anL;
        float2 xl = *(const float2*)(lrow + a * 2);
        float x0 = xl.x, x1 = xl.y;
        float mx = fmaxf(x0, x1);
        float lse = mx + logf(expf(x0 - mx) + expf(x1 - mx));
        unsigned key = 0;
        if (v < 0) {
            float closs = lse - x0;   // label 0; closs > 0
            unsigned bits = __float_as_uint(closs);
            key = bits ^ ((bits & 0x80000000u) ? 0xFFFFFFFFu : 0x80000000u);
            atomicAdd(&lhist[wave][vbin(closs)], 1u);
        } else {
            int m = v;
            int lab = slab[m];
            float xc = (lab >= 1) ? x1 : x0;   // NC==2
            pos_sum += lse - xc;
            pos_cnt += 1.0f;
            float dcx = an.x, dcy = an.y, dw = an.z, dh = an.w;
            float bx0 = sgb[m * 4], by0 = sgb[m * 4 + 1];
            float bx1 = sgb[m * 4 + 2], by1 = sgb[m * 4 + 3];
            float gcx = (bx0 + bx1) * 0.5f, gcy = (by0 + by1) * 0.5f;
            float gw = bx1 - bx0, gh = by1 - by0;
            float off0 = ((gcx - dcx) / dw) / VAR_C;
            float off1 = ((gcy - dcy) / dh) / VAR_C;
            float off2 = logf(fmaxf(gw / dw, 1e-6f)) / VAR_S;
            float off3 = logf(fmaxf(gh / dh, 1e-6f)) / VAR_S;
            float4 bp = *(const float4*)(box_preds + ((size_t)b * A + a) * 4);
            box_sum += sl1(bp.x - off0) + sl1(bp.y - off1) +
                       sl1(bp.z - off2) + sl1(bp.w - off3);
            if (lab == 1) {  // FACE
                face_cnt += 1.0f;
                const float* lp = lmk_preds + ((size_t)b * A + a) * (NL * 2);
                #pragma unroll
                for (int i = 0; i < NL; ++i) {
                    float tx = ((slmk[m * NL * 2 + 2 * i] - dcx) / dw) / VAR_C;
                    float ty = ((slmk[m * NL * 2 + 2 * i + 1] - dcy) / dh) / VAR_C;
                    lmk_sum += sl1(lp[2 * i] - tx) + sl1(lp[2 * i + 1] - ty);
                }
                const float* gp = gaze_preds + ((size_t)b * A + a) * 2;
                gaze_sum += sl1(gp[0] - sgz[m * 2]) + sl1(gp[1] - sgz[m * 2 + 1]);
            }
        }
        krow[a] = key;
    }

    // ---- epilogue: wave shfl reduce + 1 LDS hop (2 barriers total) ----
    #pragma unroll
    for (int off = 32; off > 0; off >>= 1) {
        pos_sum += __shfl_down(pos_sum, off);
        box_sum += __shfl_down(box_sum, off);
        lmk_sum += __shfl_down(lmk_sum, off);
        gaze_sum += __shfl_down(gaze_sum, off);
        pos_cnt += __shfl_down(pos_cnt, off);
        face_cnt += __shfl_down(face_cnt, off);
    }
    if (lane == 0) {
        wred[wave][0] = pos_sum; wred[wave][1] = box_sum;
        wred[wave][2] = lmk_sum; wred[wave][3] = gaze_sum;
        wred[wave][4] = pos_cnt; wred[wave][5] = face_cnt;
    }
    __syncthreads();   // wred + lhist + sbest all complete
    if (tid < 6) {
        psplit[(b * MSPLIT + s) * PF + tid] =
            wred[0][tid] + wred[1][tid] + wred[2][tid] + wred[3][tid];
    }
    bhist[(b * MSPLIT + s) * NB2 + tid] =
        lhist[0][tid] + lhist[1][tid] + lhist[2][tid] + lhist[3][tid];
    if (tid < G) {
        int ci = sinv[tid];
        gsplit[((size_t)b * MSPLIT + s) * G + tid] = (ci >= 0) ? sbest[ci] : 0ULL;
    }
}

// ---------------------------------------------------------------------------
// K2 select: grid B x 512.  Wave-0 shfl suffix scans (no block-wide scans),
// per-wave radix hists (8x contention cut), ballot-aggregated compaction,
// forced-match fixup, last-block finalize via gdone.
// ---------------------------------------------------------------------------
__global__ __launch_bounds__(ST) void select_kernel(
    const float* __restrict__ cls_logits, const float* __restrict__ box_preds,
    const float* __restrict__ lmk_preds, const float* __restrict__ gaze_preds,
    const float* __restrict__ anchors, const float* __restrict__ gt_boxes,
    const int* __restrict__ gt_labels, const float* __restrict__ gt_lmk,
    const float* __restrict__ gt_gaze, const signed char* __restrict__ matches,
    const unsigned long long* __restrict__ gsplit,
    unsigned* __restrict__ negkey, const unsigned* __restrict__ bhist,
    const float* __restrict__ psplit, unsigned* __restrict__ candbuf,
    float* __restrict__ partials, unsigned* __restrict__ gdone,
    float* __restrict__ out)
{
    const int b = blockIdx.x, tid = threadIdx.x;
    const int lane = tid & 63, wv = tid >> 6;
    __shared__ unsigned lhist[NB2];
    __shared__ unsigned whist[NW][256];
    __shared__ float accs[8];
    __shared__ float swred[NW];
    __shared__ int s_t, s_fin;
    __shared__ unsigned s_kk, s_candN, s_pfx, s_k2;

    unsigned* krow = negkey + (size_t)b * A;
    const uint4* krow4 = (const uint4*)krow;
    const float* lrow = cls_logits + (size_t)b * A * NC;
    unsigned* cand = candbuf + (size_t)b * CANDCAP;

    // ---- phase 0: merge psplit + bhist ----
    if (tid < 6) {
        float v = 0;
        for (int s2 = 0; s2 < MSPLIT; ++s2) v += psplit[(b * MSPLIT + s2) * PF + tid];
        accs[tid] = v;
    }
    if (tid < NB2) {
        unsigned v = 0;
        const unsigned* hb = bhist + (size_t)b * MSPLIT * NB2 + tid;
        for (int s2 = 0; s2 < MSPLIT; ++s2) v += hb[s2 * NB2];
        lhist[tid] = v;
    }
    if (tid == 0) s_candN = 0;
    __syncthreads();

    // ---- phase 1: fixup (forced matches) ----
    float f0 = 0, f1 = 0, f2 = 0, f3 = 0, f4 = 0, f5 = 0;
    int fbin = -1, fa = -1;
    if (tid < 32) {
        const int g = tid;
        int lab = gt_labels[b * G + g];
        unsigned long long kb = 0ULL;
        const unsigned long long* gs = gsplit + (size_t)b * MSPLIT * G + g;
        for (int s2 = 0; s2 < MSPLIT; ++s2) {
            unsigned long long v = gs[(size_t)s2 * G];
            if (v > kb) kb = v;
        }
        int a_c = -1;
        if (lab > 0 && kb != 0ULL) {
            unsigned a = 0xFFFFFFFFu - (unsigned)(kb & 0xFFFFFFFFu);
            if (matches[(size_t)b * A + a] < 0) a_c = (int)a;   // threshold wins
        }
        bool win = a_c >= 0;
        for (int j = 0; j < 32; ++j) {                 // last-wins dedup
            int aj = __shfl(a_c, j);
            if (j > g && a_c >= 0 && aj == a_c) win = false;
        }
        if (win) {
            const int a = a_c;
            float2 xl = *(const float2*)(lrow + a * 2);
            float x0 = xl.x, x1 = xl.y;
            float mx = fmaxf(x0, x1);
            float lse = mx + logf(expf(x0 - mx) + expf(x1 - mx));
            float xc = (lab >= 1) ? x1 : x0;
            f0 = lse - xc; f4 = 1.0f;
            float4 an = *(const float4*)(anchors + a * 4);
            const float* gb = gt_boxes + (b * G + g) * 4;
            float bx0 = gb[0], by0 = gb[1], bx1 = gb[2], by1 = gb[3];
            float gcx = (bx0 + bx1) * 0.5f, gcy = (by0 + by1) * 0.5f;
            float gw = bx1 - bx0, gh = by1 - by0;
            float off0 = ((gcx - an.x) / an.z) / VAR_C;
            float off1 = ((gcy - an.y) / an.w) / VAR_C;
            float off2 = logf(fmaxf(gw / an.z, 1e-6f)) / VAR_S;
            float off3 = logf(fmaxf(gh / an.w, 1e-6f)) / VAR_S;
            float4 bp = *(const float4*)(box_preds + ((size_t)b * A + a) * 4);
            f1 = sl1(bp.x - off0) + sl1(bp.y - off1) +
                 sl1(bp.z - off2) + sl1(bp.w - off3);
            if (lab == 1) {
                f5 = 1.0f;
                const float* gl = gt_lmk + (b * G + g) * NL * 2;
                const float* lp = lmk_preds + ((size_t)b * A + a) * (NL * 2);
                #pragma unroll
                for (int i = 0; i < NL; ++i) {
                    float tx = ((gl[2 * i] - an.x) / an.z) / VAR_C;
                    float ty = ((gl[2 * i + 1] - an.y) / an.w) / VAR_C;
                    f2 += sl1(lp[2 * i] - tx) + sl1(lp[2 * i + 1] - ty);
                }
                const float* gz = gt_gaze + (b * G + g) * 2;
                const float* gp = gaze_preds + ((size_t)b * A + a) * 2;
                f3 = sl1(gp[0] - gz[0]) + sl1(gp[1] - gz[1]);
            }
            unsigned key = krow[a];
            float closs = __uint_as_float(key ^ 0x80000000u);
            fbin = vbin(closs); fa = a;
        }
    }
    if (tid < 64) {   // wave 0 reduces (lanes 32..63 carry zeros)
        #pragma unroll
        for (int off = 16; off > 0; off >>= 1) {
            f0 += __shfl_down(f0, off); f1 += __shfl_down(f1, off);
            f2 += __shfl_down(f2, off); f3 += __shfl_down(f3, off);
            f4 += __shfl_down(f4, off); f5 += __shfl_down(f5, off);
        }
        if (tid == 0) {
            accs[0] += f0; accs[1] += f1; accs[2] += f2;
            accs[3] += f3; accs[4] += f4; accs[5] += f5;
        }
    }
    if (fbin >= 0) {
        atomicSub(&lhist[fbin], 1u);
        krow[fa] = 0u;     // now positive: excluded from neg scans
    }
    __syncthreads();

    // ---- phase 2: k + threshold bin (wave-0 shfl suffix scan) ----
    unsigned pos_t = (unsigned)accs[4];
    unsigned face_t = (unsigned)accs[5];
    unsigned num_pos = pos_t > 1u ? pos_t : 1u;
    unsigned neg_cnt = (unsigned)A - pos_t;
    unsigned k = 3u * num_pos; if (neg_cnt < k) k = neg_cnt;

    if (tid < 64) {
        unsigned c[4]; unsigned csum = 0;
        #pragma unroll
        for (int j = 0; j < 4; ++j) { c[j] = lhist[tid * 4 + j]; csum += c[j]; }
        unsigned S = csum;
        #pragma unroll
        for (int off = 1; off < 64; off <<= 1) {
            unsigned t2 = __shfl_down(S, off);
            if (tid + off < 64) S += t2;
        }
        unsigned excl = S - csum;
        if (excl < k && excl + csum >= k) {    // unique owner lane
            unsigned cum = excl;
            #pragma unroll
            for (int j = 3; j >= 0; --j) {
                unsigned h = c[j];
                if (cum + h >= k) { s_t = tid * 4 + j; s_kk = k - cum; break; }
                cum += h;
            }
        }
    }
    __syncthreads();
    const int t = s_t;
    const unsigned kk_bin = s_kk;

    // ---- phase 3: fused sum(bins>t) + ballot-aggregated compact(bin==t) ----
    float nsum_top = 0.0f;
    for (int i = tid; i < A / 4; i += ST) {
        uint4 kv = krow4[i];
        #pragma unroll
        for (int j = 0; j < 4; ++j) {
            unsigned key = (&kv.x)[j];
            bool cp = false;
            if (key != 0u) {
                float closs = __uint_as_float(key ^ 0x80000000u);
                int bin = vbin(closs);
                if (bin > t) nsum_top += closs;
                else if (bin == t) cp = true;
            }
            unsigned long long m = __ballot(cp);
            if (m != 0ULL) {
                int leader = __ffsll((long long)m) - 1;
                unsigned base = 0u;
                if (lane == leader)
                    base = atomicAdd(&s_candN, (unsigned)__popcll(m));
                base = __shfl(base, leader);
                if (cp) {
                    unsigned idx = base + (unsigned)__popcll(m & ((1ULL << lane) - 1ULL));
                    if (idx < CANDCAP) cand[idx] = key;
                }
            }
        }
    }
    __syncthreads();
    const unsigned candN = s_candN;
    const bool fast = candN <= CANDCAP;

    // ---- phase 4: exact radix select within bin t (per-wave hists) ----
    unsigned pfx = 0, kk = kk_bin;
    for (int p = 0; p < 4; ++p) {
        for (int i = tid; i < NW * 256; i += ST) ((unsigned*)whist)[i] = 0u;
        __syncthreads();
        const int shift = 24 - 8 * p;
        if (fast) {
            for (unsigned i = tid; i < candN; i += ST) {
                unsigned key = cand[i];
                if (p == 0 || (key >> (shift + 8)) == pfx)
                    atomicAdd(&whist[wv][(key >> shift) & 0xFFu], 1u);
            }
        } else {   // overflow fallback: full row with bin filter
            for (int a = tid; a < A; a += ST) {
                unsigned key = krow[a];
                if (key != 0u && vbin(__uint_as_float(key ^ 0x80000000u)) == t &&
                    (p == 0 || (key >> (shift + 8)) == pfx))
                    atomicAdd(&whist[wv][(key >> shift) & 0xFFu], 1u);
            }
        }
        __syncthreads();
        if (tid < 64) {
            unsigned c[4]; unsigned csum = 0;
            #pragma unroll
            for (int j = 0; j < 4; ++j) {
                unsigned v = 0;
                #pragma unroll
                for (int w = 0; w < NW; ++w) v += whist[w][tid * 4 + j];
                c[j] = v; csum += v;
            }
            unsigned S = csum;
            #pragma unroll
            for (int off = 1; off < 64; off <<= 1) {
                unsigned t2 = __shfl_down(S, off);
                if (tid + off < 64) S += t2;
            }
            unsigned excl = S - csum;
            if (excl < kk && excl + csum >= kk) {
                unsigned cum = excl;
                #pragma unroll
                for (int j = 3; j >= 0; --j) {
                    unsigned h = c[j];
                    if (cum + h >= kk) {
                        s_pfx = (pfx << 8) | (unsigned)(tid * 4 + j);
                        s_k2 = kk - cum;
                        break;
                    }
                    cum += h;
                }
            }
        }
        __syncthreads();
        pfx = s_pfx; kk = s_k2;
    }
    const unsigned Tkey = pfx;
    const unsigned krem = kk;
    const float Tval = __uint_as_float(Tkey ^ 0x80000000u);

    // ---- phase 5: candidate sum + wave reduce ----
    float csum2 = 0.0f;
    if (fast) {
        for (unsigned i = tid; i < candN; i += ST) {
            unsigned key = cand[i];
            if (key > Tkey) csum2 += __uint_as_float(key ^ 0x80000000u);
        }
    } else {
        for (int a = tid; a < A; a += ST) {
            unsigned key = krow[a];
            if (key != 0u) {
                float closs = __uint_as_float(key ^ 0x80000000u);
                if (vbin(closs) == t && key > Tkey) csum2 += closs;
            }
        }
    }
    float tot = nsum_top + csum2;
    #pragma unroll
    for (int off = 32; off > 0; off >>= 1) tot += __shfl_down(tot, off);
    if (lane == 0) swred[wv] = tot;
    __syncthreads();
    if (tid == 0) {
        float r = 0;
        #pragma unroll
        for (int w = 0; w < NW; ++w) r += swred[w];
        float* pr = partials + b * PF;
        pr[0] = accs[0]; pr[1] = accs[1]; pr[2] = accs[2]; pr[3] = accs[3];
        pr[4] = r + (float)krem * Tval;
        pr[5] = (float)num_pos;
        pr[6] = (float)(face_t > 1u ? face_t : 1u);
        __threadfence();
        unsigned r2 = atomicAdd(gdone, 1u);
        s_fin = (r2 == B - 1);
    }
    __syncthreads();
    if (!s_fin) return;
    __threadfence();   // acquire: all partials visible

    // ---- finalize (last block, wave 0) ----
    if (tid < 64) {
        int tt = tid;
        float ps = partials[tt * PF + 0], bs = partials[tt * PF + 1];
        float ls = partials[tt * PF + 2], gs = partials[tt * PF + 3];
        float ns = partials[tt * PF + 4], npos = partials[tt * PF + 5];
        float nf = partials[tt * PF + 6];
        #pragma unroll
        for (int o = 32; o > 0; o >>= 1) {
            ps += __shfl_down(ps, o); bs += __shfl_down(bs, o);
            ls += __shfl_down(ls, o); gs += __shfl_down(gs, o);
            ns += __shfl_down(ns, o); npos += __shfl_down(npos, o);
            nf += __shfl_down(nf, o);
        }
        if (tt == 0) {
            float tc = (ps + ns) / npos;
            float tb = bs / npos;
            float tl = ls / nf;
            float tg = gs / nf;
            out[0] = tc + 1.0f * tb + 0.5f * tl + 1.0f * tg;
            out[1] = tc; out[2] = tb; out[3] = tl; out[4] = tg;
        }
    }
}

extern "C" void kernel_launch(void* const* d_in, const int* in_sizes, int n_in,
                              void* d_out, int out_size, void* d_ws, size_t ws_size,
                              hipStream_t stream) {
    const float* cls_logits = (const float*)d_in[0];
    const float* box_preds  = (const float*)d_in[1];
    const float* lmk_preds  = (const float*)d_in[2];
    const float* gaze_preds = (const float*)d_in[3];
    const float* anchors    = (const float*)d_in[4];
    const float* gt_boxes   = (const float*)d_in[5];
    const int*   gt_labels  = (const int*)d_in[6];
    const float* gt_lmk     = (const float*)d_in[7];
    const float* gt_gaze    = (const float*)d_in[8];

    char* ws = (char*)d_ws;
    signed char* matches = (signed char*)ws;             ws += (size_t)B * A;                // 1.6 MB
    unsigned long long* gsplit = (unsigned long long*)ws; ws += (size_t)B * MSPLIT * G * 8;  // 0.82 MB
    unsigned* negkey = (unsigned*)ws;                    ws += (size_t)B * A * 4;            // 6.5 MB
    unsigned* bhist = (unsigned*)ws;                     ws += (size_t)B * MSPLIT * NB2 * 4; // 3.3 MB
    unsigned* candbuf = (unsigned*)ws;                   ws += (size_t)B * CANDCAP * 4;      // 2 MB
    float* psplit = (float*)ws;                          ws += (size_t)B * MSPLIT * PF * 4;  // 102 KB
    float* partials = (float*)ws;                        ws += (size_t)B * PF * 4;           // 2 KB
    unsigned* gdone = (unsigned*)ws;                     ws += 4;
    float* out = (float*)d_out;

    hipLaunchKernelGGL(fused_kernel, dim3(B, MSPLIT), dim3(256), 0, stream,
                       cls_logits, box_preds, lmk_preds, gaze_preds, anchors,
                       gt_boxes, gt_labels, gt_lmk, gt_gaze, matches, gsplit,
                       negkey, bhist, psplit, gdone);
    hipLaunchKernelGGL(select_kernel, dim3(B), dim3(ST), 0, stream,
                       cls_logits, box_preds, lmk_preds, gaze_preds, anchors,
                       gt_boxes, gt_labels, gt_lmk, gt_gaze, matches, gsplit,
                       negkey, bhist, psplit, candbuf, partials, gdone, out);
}